// Round 1
// baseline (1766.241 us; speedup 1.0000x reference)
//
#include <hip/hip_runtime.h>
#include <math.h>
#include <stdint.h>

#define N_C 60000
#define N_V 256
#define CH 128
#define NH 4
#define HD 32
#define NL 3
#define NE1 600000
#define NE2 240000

#define CDIV(a,b) (((a)+(b)-1)/(b))

__device__ __forceinline__ float gelu_tanh(float x) {
    float x3 = x * x * x;
    float t = tanhf(0.7978845608028654f * (x + 0.044715f * x3));
    return 0.5f * x * (1.0f + t);
}

// ---------------- weight composition: W~q = Wq . arel  (prel/sqrt(D) folded) ---
__global__ __launch_bounds__(256) void compose_wq(
    const float* __restrict__ Wq, const float* __restrict__ bq,
    const float* __restrict__ arel, const float* __restrict__ prel,
    float* __restrict__ WQT, float* __restrict__ BQT)
{
    int gid = blockIdx.x * blockDim.x + threadIdx.x;
    const int total = NL * 2 * (CH + 1) * CH;
    if (gid >= total) return;
    int li2 = gid / ((CH + 1) * CH);
    int rem = gid % ((CH + 1) * CH);
    int c   = rem / CH;          // 0..CH ; CH => bias row
    int col = rem % CH;
    int h = col >> 5, d = col & 31;
    const float* ar = arel + (li2 * NH + h) * (HD * HD) + d * HD;  // [e]
    float scale = prel[li2 * NH + h] * 0.17677669529663687f;       // prel/sqrt(32)
    const float* src = (c < CH) ? (Wq + ((size_t)li2 * CH + c) * CH + h * HD)
                                : (bq + li2 * CH + h * HD);
    float acc = 0.f;
    #pragma unroll
    for (int e = 0; e < HD; e++) acc = fmaf(src[e], ar[e], acc);
    acc *= scale;
    if (c < CH) WQT[((size_t)li2 * CH + c) * CH + col] = acc;
    else        BQT[li2 * CH + col] = acc;
}

// ---------------- CSR build ---------------------------------------------------
__global__ void hist_kernel(const int* __restrict__ dst, int E, int* __restrict__ deg) {
    int i = blockIdx.x * blockDim.x + threadIdx.x;
    if (i < E) atomicAdd(&deg[dst[i]], 1);
}

__global__ __launch_bounds__(1024) void scan_kernel(const int* __restrict__ deg,
                                                    int* __restrict__ rs, int n) {
    __shared__ int sums[1024];
    int t = threadIdx.x;
    int chunk = CDIV(n, 1024);
    int start = t * chunk, end = min(start + chunk, n);
    int s = 0;
    for (int i = start; i < end; i++) s += deg[i];
    sums[t] = s;
    __syncthreads();
    for (int off = 1; off < 1024; off <<= 1) {
        int v = (t >= off) ? sums[t - off] : 0;
        __syncthreads();
        sums[t] += v;
        __syncthreads();
    }
    int run = (t > 0) ? sums[t - 1] : 0;
    for (int i = start; i < end; i++) { rs[i] = run; run += deg[i]; }
    if (t == 0) rs[n] = sums[1023];
}

__global__ void scatter_kernel(const int* __restrict__ src, const int* __restrict__ dst,
                               int E, const int* __restrict__ rs, int* __restrict__ cur,
                               int* __restrict__ csr) {
    int i = blockIdx.x * blockDim.x + threadIdx.x;
    if (i < E) {
        int d = dst[i];
        int p = atomicAdd(&cur[d], 1);
        csr[rs[d] + p] = src[i];
    }
}

// ---------------- fp32 GEMM: out[M,128] = A[M,128] @ W[128,128] + bias ---------
// optional skip epilogue: out = g*(..) + (1-g)*xold, g = sigmoid(*gate)
__global__ __launch_bounds__(256) void gemm128(
    const float* __restrict__ A, const float* __restrict__ W,
    const float* __restrict__ bias, float* out, int M,
    const float* __restrict__ gate, const float* xold)
{
    __shared__ float As[32][64];
    __shared__ float Bs[32][128];
    int tid = threadIdx.x;
    int row0 = blockIdx.x * 64;
    int tx = tid & 31;   // col group -> cols tx*4..+3
    int ty = tid >> 5;   // row group -> rows ty*8..+7
    float acc[8][4] = {};
    for (int k0 = 0; k0 < 128; k0 += 32) {
        #pragma unroll
        for (int i = 0; i < 2; i++) {
            int slot = tid + i * 256;            // [0,512)
            int r = slot >> 3, kq = slot & 7;
            int rr = row0 + r;
            float4 v = make_float4(0.f, 0.f, 0.f, 0.f);
            if (rr < M) v = *(const float4*)(A + (size_t)rr * 128 + k0 + kq * 4);
            As[kq * 4 + 0][r] = v.x; As[kq * 4 + 1][r] = v.y;
            As[kq * 4 + 2][r] = v.z; As[kq * 4 + 3][r] = v.w;
        }
        #pragma unroll
        for (int i = 0; i < 4; i++) {
            int slot = tid + i * 256;            // [0,1024)
            int kr = slot >> 5, cq = slot & 31;
            float4 v = *(const float4*)(W + (size_t)(k0 + kr) * 128 + cq * 4);
            *(float4*)&Bs[kr][cq * 4] = v;
        }
        __syncthreads();
        #pragma unroll
        for (int k = 0; k < 32; k++) {
            float a[8], b[4];
            #pragma unroll
            for (int i = 0; i < 8; i++) a[i] = As[k][ty * 8 + i];
            #pragma unroll
            for (int j = 0; j < 4; j++) b[j] = Bs[k][tx * 4 + j];
            #pragma unroll
            for (int i = 0; i < 8; i++)
                #pragma unroll
                for (int j = 0; j < 4; j++) acc[i][j] = fmaf(a[i], b[j], acc[i][j]);
        }
        __syncthreads();
    }
    float g = 1.f, og = 0.f;
    if (gate != nullptr) { g = 1.f / (1.f + expf(-gate[0])); og = 1.f - g; }
    #pragma unroll
    for (int i = 0; i < 8; i++) {
        int r = row0 + ty * 8 + i;
        if (r >= M) continue;
        #pragma unroll
        for (int j = 0; j < 4; j++) {
            int c = tx * 4 + j;
            float v = acc[i][j] + bias[c];
            if (gate != nullptr) v = g * v + og * xold[(size_t)r * 128 + c];
            out[(size_t)r * 128 + c] = v;
        }
    }
}

// ---------------- HGT attention (online softmax over CSR) ---------------------
// qt: transformed+scaled q per dst node; kc/vc: raw per src node; agg may alias qt.
template<int WPN, int NPB>
__global__ void attn_hgt(const float* qt, const float* __restrict__ kc,
                         const float* __restrict__ vc,
                         const int* __restrict__ rowstart, const int* __restrict__ csr,
                         float* agg, int n_dst)
{
    int lane = threadIdx.x & 63;
    int wid  = threadIdx.x >> 6;
    int w    = wid % WPN;
    int node = blockIdx.x * NPB + wid / WPN;
    if constexpr (WPN == 1) { if (node >= n_dst) return; }

    float2 q = *(const float2*)(qt + (size_t)node * 128 + lane * 2);
    int rs = rowstart[node], re = rowstart[node + 1];
    int cnt = re - rs;
    int per = (cnt + WPN - 1) / WPN;
    int e0 = rs + w * per;
    int e1 = min(e0 + per, re);

    float m = -INFINITY, s = 0.f;
    float2 acc = make_float2(0.f, 0.f);
    for (int e = e0; e < e1; e++) {
        int sidx = csr[e];
        float2 k2 = *(const float2*)(kc + (size_t)sidx * 128 + lane * 2);
        float2 v2 = *(const float2*)(vc + (size_t)sidx * 128 + lane * 2);
        float p = fmaf(q.x, k2.x, q.y * k2.y);
        p += __shfl_xor(p, 8, 64);
        p += __shfl_xor(p, 4, 64);
        p += __shfl_xor(p, 2, 64);
        p += __shfl_xor(p, 1, 64);          // per-head dot, heads = 16-lane groups
        float nm = fmaxf(m, p);
        float sc = expf(m - nm);
        float wg = expf(p - nm);
        s = s * sc + wg;
        acc.x = fmaf(wg, v2.x, acc.x * sc);
        acc.y = fmaf(wg, v2.y, acc.y * sc);
        m = nm;
    }

    if constexpr (WPN == 1) {
        float2 o;
        o.x = (s > 0.f) ? acc.x / s : 0.f;
        o.y = (s > 0.f) ? acc.y / s : 0.f;
        *(float2*)(agg + (size_t)node * 128 + lane * 2) = o;
    } else {
        __shared__ float sm_m[WPN][4], sm_s[WPN][4];
        __shared__ float sm_a[WPN][128];
        *(float2*)&sm_a[w][lane * 2] = acc;
        if ((lane & 15) == 0) { sm_m[w][lane >> 4] = m; sm_s[w][lane >> 4] = s; }
        __syncthreads();
        if (threadIdx.x < 64) {
            int h = lane >> 4;
            float M = -INFINITY;
            #pragma unroll
            for (int i = 0; i < WPN; i++) M = fmaxf(M, sm_m[i][h]);
            float S = 0.f; float2 A = make_float2(0.f, 0.f);
            if (M != -INFINITY) {
                #pragma unroll
                for (int i = 0; i < WPN; i++) {
                    float mi = sm_m[i][h];
                    float ei = (mi == -INFINITY) ? 0.f : expf(mi - M);
                    S   += sm_s[i][h] * ei;
                    A.x += sm_a[i][lane * 2] * ei;
                    A.y += sm_a[i][lane * 2 + 1] * ei;
                }
            }
            float2 o;
            o.x = (S > 0.f) ? A.x / S : 0.f;
            o.y = (S > 0.f) ? A.y / S : 0.f;
            *(float2*)(agg + (size_t)node * 128 + lane * 2) = o;
        }
    }
}

// ---------------- per-head mrel transform + gelu, in-place [n,128] ------------
__global__ __launch_bounds__(256) void transform_gelu(float* data,
    const float* __restrict__ mrel, int n)
{
    __shared__ float rowbuf[2][128];
    int tid = threadIdx.x;
    int lr = tid >> 7;
    int col = tid & 127;
    int r = blockIdx.x * 2 + lr;
    float x = 0.f;
    if (r < n) x = data[(size_t)r * 128 + col];
    rowbuf[lr][col] = x;
    __syncthreads();
    if (r < n) {
        int h = col >> 5, e = col & 31;
        const float* mr = mrel + h * (HD * HD);
        float acc = 0.f;
        #pragma unroll
        for (int d = 0; d < HD; d++)
            acc = fmaf(rowbuf[lr][h * HD + d], mr[d * HD + e], acc);
        data[(size_t)r * 128 + col] = gelu_tanh(acc);
    }
}

// ---------------- out-conv projections (C -> 1), wave per row -----------------
__global__ __launch_bounds__(256) void proj2(const float* __restrict__ x, int n,
    const float* __restrict__ w1, const float* __restrict__ b1, float* __restrict__ o1,
    const float* __restrict__ w2, const float* __restrict__ b2, float* __restrict__ o2)
{
    int lane = threadIdx.x & 63;
    int wid = threadIdx.x >> 6;
    int r = blockIdx.x * 4 + wid;
    if (r >= n) return;
    float x0 = x[(size_t)r * 128 + lane], x1 = x[(size_t)r * 128 + 64 + lane];
    float p = fmaf(x0, w1[lane], x1 * w1[64 + lane]);
    #pragma unroll
    for (int off = 32; off >= 1; off >>= 1) p += __shfl_xor(p, off, 64);
    if (lane == 0) o1[r] = p + b1[0];
    if (o2 != nullptr) {
        float q = fmaf(x0, w2[lane], x1 * w2[64 + lane]);
        #pragma unroll
        for (int off = 32; off >= 1; off >>= 1) q += __shfl_xor(q, off, 64);
        if (lane == 0) o2[r] = q + b2[0];
    }
}

// ---------------- out-conv scalar attention (block per vnode) -----------------
__global__ __launch_bounds__(256) void attn_out(
    const float* __restrict__ qo, const float* __restrict__ ko, const float* __restrict__ vo,
    const int* __restrict__ rowstart, const int* __restrict__ csr,
    const float* __restrict__ arel_o, const float* __restrict__ prel_o,
    const float* __restrict__ mrel_o, const float* __restrict__ Wa_o,
    const float* __restrict__ ba_o, float* __restrict__ outl)
{
    int node = blockIdx.x;
    float qs = qo[node] * arel_o[0] * prel_o[0];
    int rs = rowstart[node], re = rowstart[node + 1];
    float m = -INFINITY, s = 0.f, a = 0.f;
    for (int e = rs + (int)threadIdx.x; e < re; e += blockDim.x) {
        int si = csr[e];
        float lo = qs * ko[si];
        float v = vo[si];
        float nm = fmaxf(m, lo);
        float sc = expf(m - nm);
        float wg = expf(lo - nm);
        s = s * sc + wg;
        a = fmaf(wg, v, a * sc);
        m = nm;
    }
    // wave online-merge
    #pragma unroll
    for (int off = 32; off >= 1; off >>= 1) {
        float m2 = __shfl_xor(m, off, 64);
        float s2 = __shfl_xor(s, off, 64);
        float a2 = __shfl_xor(a, off, 64);
        float M = fmaxf(m, m2);
        if (M == -INFINITY) { s = 0.f; a = 0.f; m = M; }
        else {
            float e1 = (m  == -INFINITY) ? 0.f : expf(m  - M);
            float e2 = (m2 == -INFINITY) ? 0.f : expf(m2 - M);
            s = s * e1 + s2 * e2;
            a = a * e1 + a2 * e2;
            m = M;
        }
    }
    __shared__ float smm[4], sms[4], sma[4];
    int lane = threadIdx.x & 63, wid = threadIdx.x >> 6;
    if (lane == 0) { smm[wid] = m; sms[wid] = s; sma[wid] = a; }
    __syncthreads();
    if (threadIdx.x == 0) {
        float M = -INFINITY;
        for (int i = 0; i < 4; i++) M = fmaxf(M, smm[i]);
        float S = 0.f, A = 0.f;
        if (M != -INFINITY) {
            for (int i = 0; i < 4; i++) {
                float ei = (smm[i] == -INFINITY) ? 0.f : expf(smm[i] - M);
                S += sms[i] * ei; A += sma[i] * ei;
            }
        }
        float agg = (S > 0.f) ? A / S : 0.f;
        agg *= mrel_o[0];
        outl[node] = gelu_tanh(agg) * Wa_o[0] + ba_o[0];
    }
}

// ---------------- final head: JK-max -> node_fc -> MLP ------------------------
__global__ void final_head(const float* __restrict__ outs,
    const float* __restrict__ fc_W, const float* __restrict__ fc_b,
    const float* __restrict__ W1, const float* __restrict__ b1,
    const float* __restrict__ W2, const float* __restrict__ b2,
    float* __restrict__ out)
{
    int b = threadIdx.x;
    if (b >= 64) return;
    float h = fc_b[0];
    #pragma unroll
    for (int v = 0; v < 4; v++) {
        int n = b * 4 + v;
        float jk = fmaxf(fmaxf(outs[0 * N_V + n], outs[1 * N_V + n]), outs[2 * N_V + n]);
        h = fmaf(jk, fc_W[v], h);
    }
    h = gelu_tanh(h);
    float h0 = gelu_tanh(h * W1[0] + b1[0]);
    float h1 = gelu_tanh(h * W1[1] + b1[1]);
    out[b] = h0 * W2[0] + h1 * W2[1] + b2[0];
}

// ---------------- orchestration ----------------------------------------------
extern "C" void kernel_launch(void* const* d_in, const int* in_sizes, int n_in,
                              void* d_out, int out_size, void* d_ws, size_t ws_size,
                              hipStream_t stream) {
    (void)in_sizes; (void)n_in; (void)out_size; (void)ws_size;
    const float* x_cell  = (const float*)d_in[0];
    const float* x_vcell = (const float*)d_in[1];
    const float* Wk   = (const float*)d_in[2];
    const float* bk   = (const float*)d_in[3];
    const float* Wq   = (const float*)d_in[4];
    const float* bq   = (const float*)d_in[5];
    const float* Wv   = (const float*)d_in[6];
    const float* bv   = (const float*)d_in[7];
    const float* Wa   = (const float*)d_in[8];
    const float* ba   = (const float*)d_in[9];
    const float* skip = (const float*)d_in[10];
    const float* arel = (const float*)d_in[11];
    const float* mrel = (const float*)d_in[12];
    const float* prel = (const float*)d_in[13];
    const float* Wk_o = (const float*)d_in[14];
    const float* bk_o = (const float*)d_in[15];
    const float* Wq_o = (const float*)d_in[16];
    const float* bq_o = (const float*)d_in[17];
    const float* Wv_o = (const float*)d_in[18];
    const float* bv_o = (const float*)d_in[19];
    const float* Wa_o = (const float*)d_in[20];
    const float* ba_o = (const float*)d_in[21];
    const float* arel_o = (const float*)d_in[22];
    const float* mrel_o = (const float*)d_in[23];
    const float* prel_o = (const float*)d_in[24];
    const float* fc_W  = (const float*)d_in[25];
    const float* fc_b  = (const float*)d_in[26];
    const float* mlp_W1 = (const float*)d_in[27];
    const float* mlp_b1 = (const float*)d_in[28];
    const float* mlp_W2 = (const float*)d_in[29];
    const float* mlp_b2 = (const float*)d_in[30];
    const int* src_cc = (const int*)d_in[31];
    const int* dst_cc = (const int*)d_in[32];
    const int* src_cv = (const int*)d_in[33];
    const int* dst_cv = (const int*)d_in[34];

    // workspace carve-up (256B aligned)
    char* p = (char*)d_ws;
    auto alloc = [&](size_t bytes) -> char* {
        uintptr_t q = ((uintptr_t)p + 255) & ~(uintptr_t)255;
        p = (char*)(q + bytes);
        return (char*)q;
    };
    float* WQT  = (float*)alloc(sizeof(float) * NL * 2 * CH * CH);
    float* BQT  = (float*)alloc(sizeof(float) * NL * 2 * CH);
    float* XC   = (float*)alloc(sizeof(float) * (size_t)N_C * CH);
    float* XV   = (float*)alloc(sizeof(float) * (size_t)N_V * CH);
    float* QT   = (float*)alloc(sizeof(float) * (size_t)N_C * CH);  // q~c, then agg, then G
    float* KC   = (float*)alloc(sizeof(float) * (size_t)N_C * CH);
    float* VC   = (float*)alloc(sizeof(float) * (size_t)N_C * CH);
    float* QTV  = (float*)alloc(sizeof(float) * (size_t)N_V * CH);
    float* AGGV = (float*)alloc(sizeof(float) * (size_t)N_V * CH);
    float* KO   = (float*)alloc(sizeof(float) * N_C);
    float* VO   = (float*)alloc(sizeof(float) * N_C);
    float* QO   = (float*)alloc(sizeof(float) * N_V);
    float* OUTS = (float*)alloc(sizeof(float) * NL * N_V);
    // zero region (deg + cursors), contiguous for one memset
    int* deg_cc = (int*)alloc(sizeof(int) * (2 * N_C + 2 * N_V));
    int* cur_cc = deg_cc + N_C;
    int* deg_cv = cur_cc + N_C;
    int* cur_cv = deg_cv + N_V;
    int* rs_cc  = (int*)alloc(sizeof(int) * (N_C + 1));
    int* rs_cv  = (int*)alloc(sizeof(int) * (N_V + 1));
    int* csr_cc = (int*)alloc(sizeof(int) * NE1);
    int* csr_cv = (int*)alloc(sizeof(int) * NE2);

    // ---- setup: composed weights + CSR ----
    compose_wq<<<CDIV(NL * 2 * (CH + 1) * CH, 256), 256, 0, stream>>>(
        Wq, bq, arel, prel, WQT, BQT);
    hipMemsetAsync(deg_cc, 0, sizeof(int) * (2 * N_C + 2 * N_V), stream);
    hist_kernel<<<CDIV(NE1, 256), 256, 0, stream>>>(dst_cc, NE1, deg_cc);
    hist_kernel<<<CDIV(NE2, 256), 256, 0, stream>>>(dst_cv, NE2, deg_cv);
    scan_kernel<<<1, 1024, 0, stream>>>(deg_cc, rs_cc, N_C);
    scan_kernel<<<1, 1024, 0, stream>>>(deg_cv, rs_cv, N_V);
    scatter_kernel<<<CDIV(NE1, 256), 256, 0, stream>>>(src_cc, dst_cc, NE1, rs_cc, cur_cc, csr_cc);
    scatter_kernel<<<CDIV(NE2, 256), 256, 0, stream>>>(src_cv, dst_cv, NE2, rs_cv, cur_cv, csr_cv);

    const int gb_c = CDIV(N_C, 64);
    const int gb_v = CDIV(N_V, 64);

    for (int li = 0; li < NL; li++) {
        const float* xc_src = (li == 0) ? x_cell : XC;
        const float* xv_src = (li == 0) ? x_vcell : XV;
        size_t w0 = (size_t)(li * 2) * CH * CH;      // dir0 weight offset
        size_t w1 = (size_t)(li * 2 + 1) * CH * CH;  // dir1
        int b0 = (li * 2) * CH, b1 = (li * 2 + 1) * CH;

        // q~c, kc, vc (NC x 128), q~v (NV x 128)
        gemm128<<<gb_c, 256, 0, stream>>>(xc_src, WQT + w0, BQT + b0, QT, N_C, nullptr, nullptr);
        gemm128<<<gb_c, 256, 0, stream>>>(xc_src, Wk + w0, bk + b0, KC, N_C, nullptr, nullptr);
        gemm128<<<gb_c, 256, 0, stream>>>(xc_src, Wv + w0, bv + b0, VC, N_C, nullptr, nullptr);
        gemm128<<<gb_v, 256, 0, stream>>>(xv_src, WQT + w1, BQT + b1, QTV, N_V, nullptr, nullptr);

        // cell->cell attention (raw-v agg, in-place over QT)
        attn_hgt<1, 4><<<CDIV(N_C, 4), 256, 0, stream>>>(QT, KC, VC, rs_cc, csr_cc, QT, N_C);
        transform_gelu<<<CDIV(N_C, 2), 256, 0, stream>>>(QT, mrel + (size_t)(li * 2) * NH * HD * HD, N_C);
        gemm128<<<gb_c, 256, 0, stream>>>(QT, Wa + w0, ba + b0, XC, N_C, skip + li * 2, xc_src);

        // cell->vcell attention
        attn_hgt<16, 1><<<N_V, 1024, 0, stream>>>(QTV, KC, VC, rs_cv, csr_cv, AGGV, N_V);
        transform_gelu<<<CDIV(N_V, 2), 256, 0, stream>>>(AGGV, mrel + (size_t)(li * 2 + 1) * NH * HD * HD, N_V);
        gemm128<<<gb_v, 256, 0, stream>>>(AGGV, Wa + w1, ba + b1, XV, N_V, skip + li * 2 + 1, xv_src);

        // out-conv: scalar attention on cv edges
        proj2<<<CDIV(N_C, 4), 256, 0, stream>>>(XC, N_C, Wk_o + li * CH, bk_o + li, KO,
                                                Wv_o + li * CH, bv_o + li, VO);
        proj2<<<CDIV(N_V, 4), 256, 0, stream>>>(XV, N_V, Wq_o + li * CH, bq_o + li, QO,
                                                nullptr, nullptr, nullptr);
        attn_out<<<N_V, 256, 0, stream>>>(QO, KO, VO, rs_cv, csr_cv,
                                          arel_o + li, prel_o + li, mrel_o + li,
                                          Wa_o + li, ba_o + li, OUTS + li * N_V);
    }

    final_head<<<1, 64, 0, stream>>>(OUTS, fc_W, fc_b, mlp_W1, mlp_b1, mlp_W2, mlp_b2,
                                     (float*)d_out);
}

// Round 2
// 1463.733 us; speedup vs baseline: 1.2067x; 1.2067x over previous
//
#include <hip/hip_runtime.h>
#include <math.h>
#include <stdint.h>

#define N_C 60000
#define N_V 256
#define CH 128
#define NH 4
#define HD 32
#define NL 3
#define NE1 600000
#define NE2 240000

#define CDIV(a,b) (((a)+(b)-1)/(b))
#define EPB 4096   // edges per block in CSR-build kernels

__device__ __forceinline__ float gelu_tanh(float x) {
    float x3 = x * x * x;
    float t = tanhf(0.7978845608028654f * (x + 0.044715f * x3));
    return 0.5f * x * (1.0f + t);
}

// ---------------- weight composition: W~q = Wq . arel  (prel/sqrt(D) folded) ---
__global__ __launch_bounds__(256) void compose_wq(
    const float* __restrict__ Wq, const float* __restrict__ bq,
    const float* __restrict__ arel, const float* __restrict__ prel,
    float* __restrict__ WQT, float* __restrict__ BQT)
{
    int gid = blockIdx.x * blockDim.x + threadIdx.x;
    const int total = NL * 2 * (CH + 1) * CH;
    if (gid >= total) return;
    int li2 = gid / ((CH + 1) * CH);
    int rem = gid % ((CH + 1) * CH);
    int c   = rem / CH;          // 0..CH ; CH => bias row
    int col = rem % CH;
    int h = col >> 5, d = col & 31;
    const float* ar = arel + (li2 * NH + h) * (HD * HD) + d * HD;  // [e]
    float scale = prel[li2 * NH + h] * 0.17677669529663687f;       // prel/sqrt(32)
    const float* src = (c < CH) ? (Wq + ((size_t)li2 * CH + c) * CH + h * HD)
                                : (bq + li2 * CH + h * HD);
    float acc = 0.f;
    #pragma unroll
    for (int e = 0; e < HD; e++) acc = fmaf(src[e], ar[e], acc);
    acc *= scale;
    if (c < CH) WQT[((size_t)li2 * CH + c) * CH + col] = acc;
    else        BQT[li2 * CH + col] = acc;
}

// ================= CSR build: two-level LDS counting sort =====================
// Level-0: per-block LDS histogram over digit=(dst>>shift)&255, one global
// atomicAdd (no return) per block x non-empty bin.
__global__ __launch_bounds__(256) void bucket_hist(const int* __restrict__ dst, int E,
                                                   int shift, int* __restrict__ bhist)
{
    __shared__ int h[256];
    int t = threadIdx.x;
    h[t] = 0;
    __syncthreads();
    int i0 = blockIdx.x * EPB, i1 = min(i0 + EPB, E);
    for (int i = i0 + t; i < i1; i += 256)
        atomicAdd(&h[(dst[i] >> shift) & 255], 1);
    __syncthreads();
    if (h[t] > 0) atomicAdd(&bhist[t], h[t]);
}

// 256-wide exclusive scan -> base[257]; cur[] initialized to base for cursors.
__global__ __launch_bounds__(256) void scan256(const int* __restrict__ h,
                                               int* __restrict__ base, int* __restrict__ cur)
{
    __shared__ int p[256];
    int t = threadIdx.x;
    int v = h[t];
    p[t] = v;
    __syncthreads();
    for (int off = 1; off < 256; off <<= 1) {
        int u = (t >= off) ? p[t - off] : 0;
        __syncthreads();
        p[t] += u;
        __syncthreads();
    }
    base[t] = p[t] - v;
    cur[t]  = p[t] - v;
    if (t == 255) base[256] = p[255];
}

// Level-1 partition. PAIR=true: write (src,dst) pairs grouped by bucket (cc).
// PAIR=false: digit==dst (cv), so this writes the final CSR directly.
template<bool PAIR>
__global__ __launch_bounds__(256) void partition_edges(
    const int* __restrict__ src, const int* __restrict__ dst, int E, int shift,
    int* __restrict__ cur, int2* __restrict__ tmp_pair, int* __restrict__ out_src)
{
    __shared__ int cnt[256], base[256], cnt2[256];
    int t = threadIdx.x;
    cnt[t] = 0; cnt2[t] = 0;
    __syncthreads();
    int i0 = blockIdx.x * EPB, i1 = min(i0 + EPB, E);
    for (int i = i0 + t; i < i1; i += 256)
        atomicAdd(&cnt[(dst[i] >> shift) & 255], 1);
    __syncthreads();
    if (cnt[t] > 0) base[t] = atomicAdd(&cur[t], cnt[t]);
    __syncthreads();
    for (int i = i0 + t; i < i1; i += 256) {
        int d = dst[i];
        int dig = (d >> shift) & 255;
        int r = atomicAdd(&cnt2[dig], 1);
        int pos = base[dig] + r;
        if constexpr (PAIR) tmp_pair[pos] = make_int2(src[i], d);
        else                out_src[pos] = src[i];
    }
}

// Level-2 (cc only): one block per bucket of 256 consecutive dst values.
// Produces exact per-dst CSR segment + global row starts, all in LDS.
__global__ __launch_bounds__(256) void bucket_finalize(
    const int2* __restrict__ tmp, const int* __restrict__ bbase, int n, int NE,
    int* __restrict__ rs, int* __restrict__ csr)
{
    __shared__ int cnt[256], pre[256], cnt2[256];
    int b = blockIdx.x, t = threadIdx.x;
    int s0 = bbase[b], s1 = bbase[b + 1];
    cnt[t] = 0; cnt2[t] = 0;
    __syncthreads();
    for (int i = s0 + t; i < s1; i += 256)
        atomicAdd(&cnt[tmp[i].y & 255], 1);
    __syncthreads();
    int v = cnt[t];
    pre[t] = v;
    __syncthreads();
    for (int off = 1; off < 256; off <<= 1) {
        int u = (t >= off) ? pre[t - off] : 0;
        __syncthreads();
        pre[t] += u;
        __syncthreads();
    }
    pre[t] -= v;   // exclusive
    __syncthreads();
    int dstid = b * 256 + t;
    if (dstid < n) rs[dstid] = s0 + pre[t];
    if (b == 0 && t == 0) rs[n] = NE;
    for (int i = s0 + t; i < s1; i += 256) {
        int2 e = tmp[i];
        int low = e.y & 255;
        int r = atomicAdd(&cnt2[low], 1);
        csr[s0 + pre[low] + r] = e.x;
    }
}

// ---------------- fp32 GEMM: out[M,128] = A[M,128] @ W[128,128] + bias ---------
// optional skip epilogue: out = g*(..) + (1-g)*xold, g = sigmoid(*gate)
__global__ __launch_bounds__(256) void gemm128(
    const float* __restrict__ A, const float* __restrict__ W,
    const float* __restrict__ bias, float* out, int M,
    const float* __restrict__ gate, const float* xold)
{
    __shared__ float As[32][64];
    __shared__ float Bs[32][128];
    int tid = threadIdx.x;
    int row0 = blockIdx.x * 64;
    int tx = tid & 31;   // col group -> cols tx*4..+3
    int ty = tid >> 5;   // row group -> rows ty*8..+7
    float acc[8][4] = {};
    for (int k0 = 0; k0 < 128; k0 += 32) {
        #pragma unroll
        for (int i = 0; i < 2; i++) {
            int slot = tid + i * 256;            // [0,512)
            int r = slot >> 3, kq = slot & 7;
            int rr = row0 + r;
            float4 v = make_float4(0.f, 0.f, 0.f, 0.f);
            if (rr < M) v = *(const float4*)(A + (size_t)rr * 128 + k0 + kq * 4);
            As[kq * 4 + 0][r] = v.x; As[kq * 4 + 1][r] = v.y;
            As[kq * 4 + 2][r] = v.z; As[kq * 4 + 3][r] = v.w;
        }
        #pragma unroll
        for (int i = 0; i < 4; i++) {
            int slot = tid + i * 256;            // [0,1024)
            int kr = slot >> 5, cq = slot & 31;
            float4 v = *(const float4*)(W + (size_t)(k0 + kr) * 128 + cq * 4);
            *(float4*)&Bs[kr][cq * 4] = v;
        }
        __syncthreads();
        #pragma unroll
        for (int k = 0; k < 32; k++) {
            float a[8], b[4];
            #pragma unroll
            for (int i = 0; i < 8; i++) a[i] = As[k][ty * 8 + i];
            #pragma unroll
            for (int j = 0; j < 4; j++) b[j] = Bs[k][tx * 4 + j];
            #pragma unroll
            for (int i = 0; i < 8; i++)
                #pragma unroll
                for (int j = 0; j < 4; j++) acc[i][j] = fmaf(a[i], b[j], acc[i][j]);
        }
        __syncthreads();
    }
    float g = 1.f, og = 0.f;
    if (gate != nullptr) { g = 1.f / (1.f + expf(-gate[0])); og = 1.f - g; }
    #pragma unroll
    for (int i = 0; i < 8; i++) {
        int r = row0 + ty * 8 + i;
        if (r >= M) continue;
        #pragma unroll
        for (int j = 0; j < 4; j++) {
            int c = tx * 4 + j;
            float v = acc[i][j] + bias[c];
            if (gate != nullptr) v = g * v + og * xold[(size_t)r * 128 + c];
            out[(size_t)r * 128 + c] = v;
        }
    }
}

// ---------------- HGT attention (online softmax over CSR) ---------------------
// qt: transformed+scaled q per dst node; kc/vc: raw per src node; agg may alias qt.
template<int WPN, int NPB>
__global__ void attn_hgt(const float* qt, const float* __restrict__ kc,
                         const float* __restrict__ vc,
                         const int* __restrict__ rowstart, const int* __restrict__ csr,
                         float* agg, int n_dst)
{
    int lane = threadIdx.x & 63;
    int wid  = threadIdx.x >> 6;
    int w    = wid % WPN;
    int node = blockIdx.x * NPB + wid / WPN;
    if constexpr (WPN == 1) { if (node >= n_dst) return; }

    float2 q = *(const float2*)(qt + (size_t)node * 128 + lane * 2);
    int rs = rowstart[node], re = rowstart[node + 1];
    int cnt = re - rs;
    int per = (cnt + WPN - 1) / WPN;
    int e0 = rs + w * per;
    int e1 = min(e0 + per, re);

    float m = -INFINITY, s = 0.f;
    float2 acc = make_float2(0.f, 0.f);
    for (int e = e0; e < e1; e++) {
        int sidx = csr[e];
        float2 k2 = *(const float2*)(kc + (size_t)sidx * 128 + lane * 2);
        float2 v2 = *(const float2*)(vc + (size_t)sidx * 128 + lane * 2);
        float p = fmaf(q.x, k2.x, q.y * k2.y);
        p += __shfl_xor(p, 8, 64);
        p += __shfl_xor(p, 4, 64);
        p += __shfl_xor(p, 2, 64);
        p += __shfl_xor(p, 1, 64);          // per-head dot, heads = 16-lane groups
        float nm = fmaxf(m, p);
        float sc = expf(m - nm);
        float wg = expf(p - nm);
        s = s * sc + wg;
        acc.x = fmaf(wg, v2.x, acc.x * sc);
        acc.y = fmaf(wg, v2.y, acc.y * sc);
        m = nm;
    }

    if constexpr (WPN == 1) {
        float2 o;
        o.x = (s > 0.f) ? acc.x / s : 0.f;
        o.y = (s > 0.f) ? acc.y / s : 0.f;
        *(float2*)(agg + (size_t)node * 128 + lane * 2) = o;
    } else {
        __shared__ float sm_m[WPN][4], sm_s[WPN][4];
        __shared__ float sm_a[WPN][128];
        *(float2*)&sm_a[w][lane * 2] = acc;
        if ((lane & 15) == 0) { sm_m[w][lane >> 4] = m; sm_s[w][lane >> 4] = s; }
        __syncthreads();
        if (threadIdx.x < 64) {
            int h = lane >> 4;
            float M = -INFINITY;
            #pragma unroll
            for (int i = 0; i < WPN; i++) M = fmaxf(M, sm_m[i][h]);
            float S = 0.f; float2 A = make_float2(0.f, 0.f);
            if (M != -INFINITY) {
                #pragma unroll
                for (int i = 0; i < WPN; i++) {
                    float mi = sm_m[i][h];
                    float ei = (mi == -INFINITY) ? 0.f : expf(mi - M);
                    S   += sm_s[i][h] * ei;
                    A.x += sm_a[i][lane * 2] * ei;
                    A.y += sm_a[i][lane * 2 + 1] * ei;
                }
            }
            float2 o;
            o.x = (S > 0.f) ? A.x / S : 0.f;
            o.y = (S > 0.f) ? A.y / S : 0.f;
            *(float2*)(agg + (size_t)node * 128 + lane * 2) = o;
        }
    }
}

// ---------------- per-head mrel transform + gelu, in-place [n,128] ------------
__global__ __launch_bounds__(256) void transform_gelu(float* data,
    const float* __restrict__ mrel, int n)
{
    __shared__ float rowbuf[2][128];
    int tid = threadIdx.x;
    int lr = tid >> 7;
    int col = tid & 127;
    int r = blockIdx.x * 2 + lr;
    float x = 0.f;
    if (r < n) x = data[(size_t)r * 128 + col];
    rowbuf[lr][col] = x;
    __syncthreads();
    if (r < n) {
        int h = col >> 5, e = col & 31;
        const float* mr = mrel + h * (HD * HD);
        float acc = 0.f;
        #pragma unroll
        for (int d = 0; d < HD; d++)
            acc = fmaf(rowbuf[lr][h * HD + d], mr[d * HD + e], acc);
        data[(size_t)r * 128 + col] = gelu_tanh(acc);
    }
}

// ---------------- out-conv projections (C -> 1), wave per row -----------------
__global__ __launch_bounds__(256) void proj2(const float* __restrict__ x, int n,
    const float* __restrict__ w1, const float* __restrict__ b1, float* __restrict__ o1,
    const float* __restrict__ w2, const float* __restrict__ b2, float* __restrict__ o2)
{
    int lane = threadIdx.x & 63;
    int wid = threadIdx.x >> 6;
    int r = blockIdx.x * 4 + wid;
    if (r >= n) return;
    float x0 = x[(size_t)r * 128 + lane], x1 = x[(size_t)r * 128 + 64 + lane];
    float p = fmaf(x0, w1[lane], x1 * w1[64 + lane]);
    #pragma unroll
    for (int off = 32; off >= 1; off >>= 1) p += __shfl_xor(p, off, 64);
    if (lane == 0) o1[r] = p + b1[0];
    if (o2 != nullptr) {
        float q = fmaf(x0, w2[lane], x1 * w2[64 + lane]);
        #pragma unroll
        for (int off = 32; off >= 1; off >>= 1) q += __shfl_xor(q, off, 64);
        if (lane == 0) o2[r] = q + b2[0];
    }
}

// ---------------- out-conv scalar attention (block per vnode) -----------------
__global__ __launch_bounds__(256) void attn_out(
    const float* __restrict__ qo, const float* __restrict__ ko, const float* __restrict__ vo,
    const int* __restrict__ rowstart, const int* __restrict__ csr,
    const float* __restrict__ arel_o, const float* __restrict__ prel_o,
    const float* __restrict__ mrel_o, const float* __restrict__ Wa_o,
    const float* __restrict__ ba_o, float* __restrict__ outl)
{
    int node = blockIdx.x;
    float qs = qo[node] * arel_o[0] * prel_o[0];
    int rs = rowstart[node], re = rowstart[node + 1];
    float m = -INFINITY, s = 0.f, a = 0.f;
    for (int e = rs + (int)threadIdx.x; e < re; e += blockDim.x) {
        int si = csr[e];
        float lo = qs * ko[si];
        float v = vo[si];
        float nm = fmaxf(m, lo);
        float sc = expf(m - nm);
        float wg = expf(lo - nm);
        s = s * sc + wg;
        a = fmaf(wg, v, a * sc);
        m = nm;
    }
    // wave online-merge
    #pragma unroll
    for (int off = 32; off >= 1; off >>= 1) {
        float m2 = __shfl_xor(m, off, 64);
        float s2 = __shfl_xor(s, off, 64);
        float a2 = __shfl_xor(a, off, 64);
        float M = fmaxf(m, m2);
        if (M == -INFINITY) { s = 0.f; a = 0.f; m = M; }
        else {
            float e1 = (m  == -INFINITY) ? 0.f : expf(m  - M);
            float e2 = (m2 == -INFINITY) ? 0.f : expf(m2 - M);
            s = s * e1 + s2 * e2;
            a = a * e1 + a2 * e2;
            m = M;
        }
    }
    __shared__ float smm[4], sms[4], sma[4];
    int lane = threadIdx.x & 63, wid = threadIdx.x >> 6;
    if (lane == 0) { smm[wid] = m; sms[wid] = s; sma[wid] = a; }
    __syncthreads();
    if (threadIdx.x == 0) {
        float M = -INFINITY;
        for (int i = 0; i < 4; i++) M = fmaxf(M, smm[i]);
        float S = 0.f, A = 0.f;
        if (M != -INFINITY) {
            for (int i = 0; i < 4; i++) {
                float ei = (smm[i] == -INFINITY) ? 0.f : expf(smm[i] - M);
                S += sms[i] * ei; A += sma[i] * ei;
            }
        }
        float agg = (S > 0.f) ? A / S : 0.f;
        agg *= mrel_o[0];
        outl[node] = gelu_tanh(agg) * Wa_o[0] + ba_o[0];
    }
}

// ---------------- final head: JK-max -> node_fc -> MLP ------------------------
__global__ void final_head(const float* __restrict__ outs,
    const float* __restrict__ fc_W, const float* __restrict__ fc_b,
    const float* __restrict__ W1, const float* __restrict__ b1,
    const float* __restrict__ W2, const float* __restrict__ b2,
    float* __restrict__ out)
{
    int b = threadIdx.x;
    if (b >= 64) return;
    float h = fc_b[0];
    #pragma unroll
    for (int v = 0; v < 4; v++) {
        int n = b * 4 + v;
        float jk = fmaxf(fmaxf(outs[0 * N_V + n], outs[1 * N_V + n]), outs[2 * N_V + n]);
        h = fmaf(jk, fc_W[v], h);
    }
    h = gelu_tanh(h);
    float h0 = gelu_tanh(h * W1[0] + b1[0]);
    float h1 = gelu_tanh(h * W1[1] + b1[1]);
    out[b] = h0 * W2[0] + h1 * W2[1] + b2[0];
}

// ---------------- orchestration ----------------------------------------------
extern "C" void kernel_launch(void* const* d_in, const int* in_sizes, int n_in,
                              void* d_out, int out_size, void* d_ws, size_t ws_size,
                              hipStream_t stream) {
    (void)in_sizes; (void)n_in; (void)out_size; (void)ws_size;
    const float* x_cell  = (const float*)d_in[0];
    const float* x_vcell = (const float*)d_in[1];
    const float* Wk   = (const float*)d_in[2];
    const float* bk   = (const float*)d_in[3];
    const float* Wq   = (const float*)d_in[4];
    const float* bq   = (const float*)d_in[5];
    const float* Wv   = (const float*)d_in[6];
    const float* bv   = (const float*)d_in[7];
    const float* Wa   = (const float*)d_in[8];
    const float* ba   = (const float*)d_in[9];
    const float* skip = (const float*)d_in[10];
    const float* arel = (const float*)d_in[11];
    const float* mrel = (const float*)d_in[12];
    const float* prel = (const float*)d_in[13];
    const float* Wk_o = (const float*)d_in[14];
    const float* bk_o = (const float*)d_in[15];
    const float* Wq_o = (const float*)d_in[16];
    const float* bq_o = (const float*)d_in[17];
    const float* Wv_o = (const float*)d_in[18];
    const float* bv_o = (const float*)d_in[19];
    const float* Wa_o = (const float*)d_in[20];
    const float* ba_o = (const float*)d_in[21];
    const float* arel_o = (const float*)d_in[22];
    const float* mrel_o = (const float*)d_in[23];
    const float* prel_o = (const float*)d_in[24];
    const float* fc_W  = (const float*)d_in[25];
    const float* fc_b  = (const float*)d_in[26];
    const float* mlp_W1 = (const float*)d_in[27];
    const float* mlp_b1 = (const float*)d_in[28];
    const float* mlp_W2 = (const float*)d_in[29];
    const float* mlp_b2 = (const float*)d_in[30];
    const int* src_cc = (const int*)d_in[31];
    const int* dst_cc = (const int*)d_in[32];
    const int* src_cv = (const int*)d_in[33];
    const int* dst_cv = (const int*)d_in[34];

    // workspace carve-up (256B aligned)
    char* p = (char*)d_ws;
    auto alloc = [&](size_t bytes) -> char* {
        uintptr_t q = ((uintptr_t)p + 255) & ~(uintptr_t)255;
        p = (char*)(q + bytes);
        return (char*)q;
    };
    float* WQT  = (float*)alloc(sizeof(float) * NL * 2 * CH * CH);
    float* BQT  = (float*)alloc(sizeof(float) * NL * 2 * CH);
    float* XC   = (float*)alloc(sizeof(float) * (size_t)N_C * CH);
    float* XV   = (float*)alloc(sizeof(float) * (size_t)N_V * CH);
    float* QT   = (float*)alloc(sizeof(float) * (size_t)N_C * CH);  // q~c, then agg, then G
    float* KC   = (float*)alloc(sizeof(float) * (size_t)N_C * CH);
    float* VC   = (float*)alloc(sizeof(float) * (size_t)N_C * CH);
    float* QTV  = (float*)alloc(sizeof(float) * (size_t)N_V * CH);
    float* AGGV = (float*)alloc(sizeof(float) * (size_t)N_V * CH);
    float* KO   = (float*)alloc(sizeof(float) * N_C);
    float* VO   = (float*)alloc(sizeof(float) * N_C);
    float* QO   = (float*)alloc(sizeof(float) * N_V);
    float* OUTS = (float*)alloc(sizeof(float) * NL * N_V);
    // CSR-build scratch
    int* bhist    = (int*)alloc(sizeof(int) * 512);          // [0..255] cc, [256..511] cv (zeroed)
    int* bhist_cc = bhist;
    int* bhist_cv = bhist + 256;
    int* bbase_cc = (int*)alloc(sizeof(int) * 257);
    int* cur_cc   = (int*)alloc(sizeof(int) * 256);
    int* cur_cv   = (int*)alloc(sizeof(int) * 256);
    int* rs_cc    = (int*)alloc(sizeof(int) * (N_C + 1));
    int* rs_cv    = (int*)alloc(sizeof(int) * (N_V + 1));
    int* csr_cc   = (int*)alloc(sizeof(int) * NE1);
    int* csr_cv   = (int*)alloc(sizeof(int) * NE2);
    int2* tmp_cc  = (int2*)alloc(sizeof(int2) * NE1);

    // ---- setup: composed weights + CSR (two-level counting sort) ----
    compose_wq<<<CDIV(NL * 2 * (CH + 1) * CH, 256), 256, 0, stream>>>(
        Wq, bq, arel, prel, WQT, BQT);
    hipMemsetAsync(bhist, 0, sizeof(int) * 512, stream);
    bucket_hist<<<CDIV(NE1, EPB), 256, 0, stream>>>(dst_cc, NE1, 8, bhist_cc);
    bucket_hist<<<CDIV(NE2, EPB), 256, 0, stream>>>(dst_cv, NE2, 0, bhist_cv);
    scan256<<<1, 256, 0, stream>>>(bhist_cc, bbase_cc, cur_cc);
    scan256<<<1, 256, 0, stream>>>(bhist_cv, rs_cv, cur_cv);   // rs_cv IS the cv row starts
    partition_edges<true ><<<CDIV(NE1, EPB), 256, 0, stream>>>(src_cc, dst_cc, NE1, 8,
                                                               cur_cc, tmp_cc, nullptr);
    partition_edges<false><<<CDIV(NE2, EPB), 256, 0, stream>>>(src_cv, dst_cv, NE2, 0,
                                                               cur_cv, nullptr, csr_cv);
    bucket_finalize<<<CDIV(N_C, 256), 256, 0, stream>>>(tmp_cc, bbase_cc, N_C, NE1,
                                                        rs_cc, csr_cc);

    const int gb_c = CDIV(N_C, 64);
    const int gb_v = CDIV(N_V, 64);

    for (int li = 0; li < NL; li++) {
        const float* xc_src = (li == 0) ? x_cell : XC;
        const float* xv_src = (li == 0) ? x_vcell : XV;
        size_t w0 = (size_t)(li * 2) * CH * CH;      // dir0 weight offset
        size_t w1 = (size_t)(li * 2 + 1) * CH * CH;  // dir1
        int b0 = (li * 2) * CH, b1 = (li * 2 + 1) * CH;

        // q~c, kc, vc (NC x 128), q~v (NV x 128)
        gemm128<<<gb_c, 256, 0, stream>>>(xc_src, WQT + w0, BQT + b0, QT, N_C, nullptr, nullptr);
        gemm128<<<gb_c, 256, 0, stream>>>(xc_src, Wk + w0, bk + b0, KC, N_C, nullptr, nullptr);
        gemm128<<<gb_c, 256, 0, stream>>>(xc_src, Wv + w0, bv + b0, VC, N_C, nullptr, nullptr);
        gemm128<<<gb_v, 256, 0, stream>>>(xv_src, WQT + w1, BQT + b1, QTV, N_V, nullptr, nullptr);

        // cell->cell attention (raw-v agg, in-place over QT)
        attn_hgt<1, 4><<<CDIV(N_C, 4), 256, 0, stream>>>(QT, KC, VC, rs_cc, csr_cc, QT, N_C);
        transform_gelu<<<CDIV(N_C, 2), 256, 0, stream>>>(QT, mrel + (size_t)(li * 2) * NH * HD * HD, N_C);
        gemm128<<<gb_c, 256, 0, stream>>>(QT, Wa + w0, ba + b0, XC, N_C, skip + li * 2, xc_src);

        // cell->vcell attention
        attn_hgt<16, 1><<<N_V, 1024, 0, stream>>>(QTV, KC, VC, rs_cv, csr_cv, AGGV, N_V);
        transform_gelu<<<CDIV(N_V, 2), 256, 0, stream>>>(AGGV, mrel + (size_t)(li * 2 + 1) * NH * HD * HD, N_V);
        gemm128<<<gb_v, 256, 0, stream>>>(AGGV, Wa + w1, ba + b1, XV, N_V, skip + li * 2 + 1, xv_src);

        // out-conv: scalar attention on cv edges
        proj2<<<CDIV(N_C, 4), 256, 0, stream>>>(XC, N_C, Wk_o + li * CH, bk_o + li, KO,
                                                Wv_o + li * CH, bv_o + li, VO);
        proj2<<<CDIV(N_V, 4), 256, 0, stream>>>(XV, N_V, Wq_o + li * CH, bq_o + li, QO,
                                                nullptr, nullptr, nullptr);
        attn_out<<<N_V, 256, 0, stream>>>(QO, KO, VO, rs_cv, csr_cv,
                                          arel_o + li, prel_o + li, mrel_o + li,
                                          Wa_o + li, ba_o + li, OUTS + li * N_V);
    }

    final_head<<<1, 64, 0, stream>>>(OUTS, fc_W, fc_b, mlp_W1, mlp_b1, mlp_W2, mlp_b2,
                                     (float*)d_out);
}

// Round 3
// 1425.255 us; speedup vs baseline: 1.2392x; 1.0270x over previous
//
#include <hip/hip_runtime.h>
#include <math.h>
#include <stdint.h>

#define N_C 60000
#define N_V 256
#define CH 128
#define NH 4
#define HD 32
#define NL 3
#define NE1 600000
#define NE2 240000

#define CDIV(a,b) (((a)+(b)-1)/(b))
#define EPB 4096   // edges per block in CSR-build kernels

__device__ __forceinline__ float gelu_tanh(float x) {
    float x3 = x * x * x;
    float t = tanhf(0.7978845608028654f * (x + 0.044715f * x3));
    return 0.5f * x * (1.0f + t);
}

// ---------------- weight composition: W~q = Wq . arel  (prel/sqrt(D) folded) ---
__global__ __launch_bounds__(256) void compose_wq(
    const float* __restrict__ Wq, const float* __restrict__ bq,
    const float* __restrict__ arel, const float* __restrict__ prel,
    float* __restrict__ WQT, float* __restrict__ BQT)
{
    int gid = blockIdx.x * blockDim.x + threadIdx.x;
    const int total = NL * 2 * (CH + 1) * CH;
    if (gid >= total) return;
    int li2 = gid / ((CH + 1) * CH);
    int rem = gid % ((CH + 1) * CH);
    int c   = rem / CH;          // 0..CH ; CH => bias row
    int col = rem % CH;
    int h = col >> 5, d = col & 31;
    const float* ar = arel + (li2 * NH + h) * (HD * HD) + d * HD;  // [e]
    float scale = prel[li2 * NH + h] * 0.17677669529663687f;       // prel/sqrt(32)
    const float* src = (c < CH) ? (Wq + ((size_t)li2 * CH + c) * CH + h * HD)
                                : (bq + li2 * CH + h * HD);
    float acc = 0.f;
    #pragma unroll
    for (int e = 0; e < HD; e++) acc = fmaf(src[e], ar[e], acc);
    acc *= scale;
    if (c < CH) WQT[((size_t)li2 * CH + c) * CH + col] = acc;
    else        BQT[li2 * CH + col] = acc;
}

// ================= CSR build: two-level LDS counting sort =====================
__global__ __launch_bounds__(256) void bucket_hist(const int* __restrict__ dst, int E,
                                                   int shift, int* __restrict__ bhist)
{
    __shared__ int h[256];
    int t = threadIdx.x;
    h[t] = 0;
    __syncthreads();
    int i0 = blockIdx.x * EPB, i1 = min(i0 + EPB, E);
    for (int i = i0 + t; i < i1; i += 256)
        atomicAdd(&h[(dst[i] >> shift) & 255], 1);
    __syncthreads();
    if (h[t] > 0) atomicAdd(&bhist[t], h[t]);
}

__global__ __launch_bounds__(256) void scan256(const int* __restrict__ h,
                                               int* __restrict__ base, int* __restrict__ cur)
{
    __shared__ int p[256];
    int t = threadIdx.x;
    int v = h[t];
    p[t] = v;
    __syncthreads();
    for (int off = 1; off < 256; off <<= 1) {
        int u = (t >= off) ? p[t - off] : 0;
        __syncthreads();
        p[t] += u;
        __syncthreads();
    }
    base[t] = p[t] - v;
    cur[t]  = p[t] - v;
    if (t == 255) base[256] = p[255];
}

template<bool PAIR>
__global__ __launch_bounds__(256) void partition_edges(
    const int* __restrict__ src, const int* __restrict__ dst, int E, int shift,
    int* __restrict__ cur, int2* __restrict__ tmp_pair, int* __restrict__ out_src)
{
    __shared__ int cnt[256], base[256], cnt2[256];
    int t = threadIdx.x;
    cnt[t] = 0; cnt2[t] = 0;
    __syncthreads();
    int i0 = blockIdx.x * EPB, i1 = min(i0 + EPB, E);
    for (int i = i0 + t; i < i1; i += 256)
        atomicAdd(&cnt[(dst[i] >> shift) & 255], 1);
    __syncthreads();
    if (cnt[t] > 0) base[t] = atomicAdd(&cur[t], cnt[t]);
    __syncthreads();
    for (int i = i0 + t; i < i1; i += 256) {
        int d = dst[i];
        int dig = (d >> shift) & 255;
        int r = atomicAdd(&cnt2[dig], 1);
        int pos = base[dig] + r;
        if constexpr (PAIR) tmp_pair[pos] = make_int2(src[i], d);
        else                out_src[pos] = src[i];
    }
}

__global__ __launch_bounds__(256) void bucket_finalize(
    const int2* __restrict__ tmp, const int* __restrict__ bbase, int n, int NE,
    int* __restrict__ rs, int* __restrict__ csr)
{
    __shared__ int cnt[256], pre[256], cnt2[256];
    int b = blockIdx.x, t = threadIdx.x;
    int s0 = bbase[b], s1 = bbase[b + 1];
    cnt[t] = 0; cnt2[t] = 0;
    __syncthreads();
    for (int i = s0 + t; i < s1; i += 256)
        atomicAdd(&cnt[tmp[i].y & 255], 1);
    __syncthreads();
    int v = cnt[t];
    pre[t] = v;
    __syncthreads();
    for (int off = 1; off < 256; off <<= 1) {
        int u = (t >= off) ? pre[t - off] : 0;
        __syncthreads();
        pre[t] += u;
        __syncthreads();
    }
    pre[t] -= v;   // exclusive
    __syncthreads();
    int dstid = b * 256 + t;
    if (dstid < n) rs[dstid] = s0 + pre[t];
    if (b == 0 && t == 0) rs[n] = NE;
    for (int i = s0 + t; i < s1; i += 256) {
        int2 e = tmp[i];
        int low = e.y & 255;
        int r = atomicAdd(&cnt2[low], 1);
        csr[s0 + pre[low] + r] = e.x;
    }
}

// ---------------- fused q~/k/v GEMM: A[M,128] x 3 weights -> out[M,384] --------
// A staged to LDS once; k/v land adjacent per node => 1KB contiguous gather.
__global__ __launch_bounds__(256) void gemm_qkv(
    const float* __restrict__ A, int lda, int M,
    const float* __restrict__ W0, const float* __restrict__ W1, const float* __restrict__ W2,
    const float* __restrict__ b0, const float* __restrict__ b1, const float* __restrict__ b2,
    float* __restrict__ out)
{
    __shared__ float As[128][64];   // [k][r] 32 KB
    __shared__ float Bs[32][128];   // 16 KB
    int tid = threadIdx.x;
    int row0 = blockIdx.x * 64;
    int tx = tid & 31;   // cols tx*4..+3
    int ty = tid >> 5;   // rows ty*8..+7
    #pragma unroll
    for (int i = 0; i < 8; i++) {
        int slot = tid + i * 256;            // [0,2048) float4 slots
        int r = slot >> 5, kq = slot & 31;
        int rr = row0 + r;
        float4 v = make_float4(0.f, 0.f, 0.f, 0.f);
        if (rr < M) v = *(const float4*)(A + (size_t)rr * lda + kq * 4);
        As[kq * 4 + 0][r] = v.x; As[kq * 4 + 1][r] = v.y;
        As[kq * 4 + 2][r] = v.z; As[kq * 4 + 3][r] = v.w;
    }
    const float* Ws[3] = {W0, W1, W2};
    const float* bs[3] = {b0, b1, b2};
    for (int jw = 0; jw < 3; jw++) {
        float acc[8][4] = {};
        for (int k0 = 0; k0 < 128; k0 += 32) {
            __syncthreads();
            #pragma unroll
            for (int i = 0; i < 4; i++) {
                int slot = tid + i * 256;    // [0,1024)
                int kr = slot >> 5, cq = slot & 31;
                *(float4*)&Bs[kr][cq * 4] = *(const float4*)(Ws[jw] + (size_t)(k0 + kr) * 128 + cq * 4);
            }
            __syncthreads();
            #pragma unroll
            for (int k = 0; k < 32; k++) {
                float a[8], b[4];
                #pragma unroll
                for (int i = 0; i < 8; i++) a[i] = As[k0 + k][ty * 8 + i];
                #pragma unroll
                for (int j = 0; j < 4; j++) b[j] = Bs[k][tx * 4 + j];
                #pragma unroll
                for (int i = 0; i < 8; i++)
                    #pragma unroll
                    for (int j = 0; j < 4; j++) acc[i][j] = fmaf(a[i], b[j], acc[i][j]);
            }
        }
        #pragma unroll
        for (int i = 0; i < 8; i++) {
            int r = row0 + ty * 8 + i;
            if (r >= M) continue;
            #pragma unroll
            for (int j = 0; j < 4; j++) {
                int c = tx * 4 + j;
                out[(size_t)r * 384 + jw * 128 + c] = acc[i][j] + bs[jw][c];
            }
        }
    }
}

// ---------------- fp32 GEMM: out[M,128] = A[M,lda-strided,128] @ W + bias ------
// optional skip epilogue: out = g*(..) + (1-g)*xold (stride 128)
__global__ __launch_bounds__(256) void gemm128(
    const float* __restrict__ A, int lda, const float* __restrict__ W,
    const float* __restrict__ bias, float* out, int M,
    const float* __restrict__ gate, const float* xold)
{
    __shared__ float As[32][64];
    __shared__ float Bs[32][128];
    int tid = threadIdx.x;
    int row0 = blockIdx.x * 64;
    int tx = tid & 31;
    int ty = tid >> 5;
    float acc[8][4] = {};
    for (int k0 = 0; k0 < 128; k0 += 32) {
        #pragma unroll
        for (int i = 0; i < 2; i++) {
            int slot = tid + i * 256;            // [0,512)
            int r = slot >> 3, kq = slot & 7;
            int rr = row0 + r;
            float4 v = make_float4(0.f, 0.f, 0.f, 0.f);
            if (rr < M) v = *(const float4*)(A + (size_t)rr * lda + k0 + kq * 4);
            As[kq * 4 + 0][r] = v.x; As[kq * 4 + 1][r] = v.y;
            As[kq * 4 + 2][r] = v.z; As[kq * 4 + 3][r] = v.w;
        }
        #pragma unroll
        for (int i = 0; i < 4; i++) {
            int slot = tid + i * 256;            // [0,1024)
            int kr = slot >> 5, cq = slot & 31;
            float4 v = *(const float4*)(W + (size_t)(k0 + kr) * 128 + cq * 4);
            *(float4*)&Bs[kr][cq * 4] = v;
        }
        __syncthreads();
        #pragma unroll
        for (int k = 0; k < 32; k++) {
            float a[8], b[4];
            #pragma unroll
            for (int i = 0; i < 8; i++) a[i] = As[k][ty * 8 + i];
            #pragma unroll
            for (int j = 0; j < 4; j++) b[j] = Bs[k][tx * 4 + j];
            #pragma unroll
            for (int i = 0; i < 8; i++)
                #pragma unroll
                for (int j = 0; j < 4; j++) acc[i][j] = fmaf(a[i], b[j], acc[i][j]);
        }
        __syncthreads();
    }
    float g = 1.f, og = 0.f;
    if (gate != nullptr) { g = 1.f / (1.f + expf(-gate[0])); og = 1.f - g; }
    #pragma unroll
    for (int i = 0; i < 8; i++) {
        int r = row0 + ty * 8 + i;
        if (r >= M) continue;
        #pragma unroll
        for (int j = 0; j < 4; j++) {
            int c = tx * 4 + j;
            float v = acc[i][j] + bias[c];
            if (gate != nullptr) v = g * v + og * xold[(size_t)r * 128 + c];
            out[(size_t)r * 128 + c] = v;
        }
    }
}

// ---------------- max-free edge accumulation (2-way ILP) -----------------------
// k at node*384+128, v at node*384+256. lanepair = 2*lane.
__device__ __forceinline__ void accum_edges(
    const float* xqkv, const int* __restrict__ csr,
    int e0, int e1, float qx, float qy, int lanepair,
    float& s_out, float& ax_out, float& ay_out)
{
    float s0 = 0.f, s1 = 0.f;
    float a0x = 0.f, a0y = 0.f, a1x = 0.f, a1y = 0.f;
    int e = e0;
    for (; e + 2 <= e1; e += 2) {
        int i0 = csr[e], i1 = csr[e + 1];
        const float* p0 = xqkv + (size_t)i0 * 384 + 128 + lanepair;
        const float* p1 = xqkv + (size_t)i1 * 384 + 128 + lanepair;
        float2 k0 = *(const float2*)p0, v0 = *(const float2*)(p0 + 128);
        float2 k1 = *(const float2*)p1, v1 = *(const float2*)(p1 + 128);
        float pa = fmaf(qx, k0.x, qy * k0.y);
        float pb = fmaf(qx, k1.x, qy * k1.y);
        pa += __shfl_xor(pa, 8, 64); pb += __shfl_xor(pb, 8, 64);
        pa += __shfl_xor(pa, 4, 64); pb += __shfl_xor(pb, 4, 64);
        pa += __shfl_xor(pa, 2, 64); pb += __shfl_xor(pb, 2, 64);
        pa += __shfl_xor(pa, 1, 64); pb += __shfl_xor(pb, 1, 64);
        float wa = __expf(pa), wb = __expf(pb);
        s0 += wa; s1 += wb;
        a0x = fmaf(wa, v0.x, a0x); a0y = fmaf(wa, v0.y, a0y);
        a1x = fmaf(wb, v1.x, a1x); a1y = fmaf(wb, v1.y, a1y);
    }
    if (e < e1) {
        int i0 = csr[e];
        const float* p0 = xqkv + (size_t)i0 * 384 + 128 + lanepair;
        float2 k0 = *(const float2*)p0, v0 = *(const float2*)(p0 + 128);
        float pa = fmaf(qx, k0.x, qy * k0.y);
        pa += __shfl_xor(pa, 8, 64);
        pa += __shfl_xor(pa, 4, 64);
        pa += __shfl_xor(pa, 2, 64);
        pa += __shfl_xor(pa, 1, 64);
        float wa = __expf(pa);
        s0 += wa;
        a0x = fmaf(wa, v0.x, a0x); a0y = fmaf(wa, v0.y, a0y);
    }
    s_out = s0 + s1;
    ax_out = a0x + a1x;
    ay_out = a0y + a1y;
}

// ---------------- cc attention: wave/node, fused mrel+gelu, in-place q-slot ----
__global__ __launch_bounds__(256) void attn_cc(
    float* xqkv, const int* __restrict__ rowstart, const int* __restrict__ csr,
    const float* __restrict__ mrel, int n)
{
    __shared__ float rowbuf[4][128];
    int lane = threadIdx.x & 63, wid = threadIdx.x >> 6;
    int node = blockIdx.x * 4 + wid;
    int lp = 2 * lane;
    if (node < n) {
        float2 q = *(const float2*)(xqkv + (size_t)node * 384 + lp);
        int rs = rowstart[node], re = rowstart[node + 1];
        float s, ax, ay;
        accum_edges(xqkv, csr, rs, re, q.x, q.y, lp, s, ax, ay);
        float inv = (s > 0.f) ? 1.f / s : 0.f;
        rowbuf[wid][lp]     = ax * inv;
        rowbuf[wid][lp + 1] = ay * inv;
    }
    __syncthreads();
    if (node < n) {
        int h = lp >> 5, eo = lp & 31;
        const float* mr = mrel + h * 1024 + eo;
        const float* rb = rowbuf[wid] + h * 32;
        float t0 = 0.f, t1 = 0.f;
        #pragma unroll
        for (int d = 0; d < 32; d++) {
            float a = rb[d];
            t0 = fmaf(a, mr[d * 32], t0);
            t1 = fmaf(a, mr[d * 32 + 1], t1);
        }
        xqkv[(size_t)node * 384 + lp]     = gelu_tanh(t0);
        xqkv[(size_t)node * 384 + lp + 1] = gelu_tanh(t1);
    }
}

// ---------------- cv attention: block/node (16 waves), fused mrel+gelu ---------
__global__ __launch_bounds__(1024) void attn_cv(
    const float* __restrict__ qtv, const float* __restrict__ xqkv,
    const int* __restrict__ rowstart, const int* __restrict__ csr,
    const float* __restrict__ mrel, float* __restrict__ aggv)
{
    __shared__ float sm_s[16][4];
    __shared__ float sm_a[16][128];
    __shared__ float orow[128];
    int lane = threadIdx.x & 63, w = threadIdx.x >> 6;
    int node = blockIdx.x;
    int lp = 2 * lane;
    float2 q = *(const float2*)(qtv + (size_t)node * 128 + lp);
    int rs = rowstart[node], re = rowstart[node + 1];
    int cnt = re - rs;
    int per = (cnt + 15) >> 4;
    int e0 = rs + w * per, e1 = min(e0 + per, re);
    float s, ax, ay;
    accum_edges(xqkv, csr, e0, e1, q.x, q.y, lp, s, ax, ay);
    sm_a[w][lp] = ax; sm_a[w][lp + 1] = ay;
    if ((lane & 15) == 0) sm_s[w][lane >> 4] = s;
    __syncthreads();
    if (threadIdx.x < 64) {
        int h = lane >> 4;
        float S = 0.f, AX = 0.f, AY = 0.f;
        #pragma unroll
        for (int i = 0; i < 16; i++) {
            S  += sm_s[i][h];
            AX += sm_a[i][lp];
            AY += sm_a[i][lp + 1];
        }
        float inv = (S > 0.f) ? 1.f / S : 0.f;
        orow[lp] = AX * inv; orow[lp + 1] = AY * inv;
        // intra-wave LDS ordering: DS ops of one wave execute in program order
        int eo = lp & 31;
        const float* mr = mrel + h * 1024 + eo;
        const float* rb = orow + h * 32;
        float t0 = 0.f, t1 = 0.f;
        #pragma unroll
        for (int d = 0; d < 32; d++) {
            float a = rb[d];
            t0 = fmaf(a, mr[d * 32], t0);
            t1 = fmaf(a, mr[d * 32 + 1], t1);
        }
        aggv[(size_t)node * 128 + lp]     = gelu_tanh(t0);
        aggv[(size_t)node * 128 + lp + 1] = gelu_tanh(t1);
    }
}

// ---------------- out-conv projections (C -> 1), wave per row -----------------
__global__ __launch_bounds__(256) void proj2(const float* __restrict__ x, int n,
    const float* __restrict__ w1, const float* __restrict__ b1, float* __restrict__ o1,
    const float* __restrict__ w2, const float* __restrict__ b2, float* __restrict__ o2)
{
    int lane = threadIdx.x & 63;
    int wid = threadIdx.x >> 6;
    int r = blockIdx.x * 4 + wid;
    if (r >= n) return;
    float x0 = x[(size_t)r * 128 + lane], x1 = x[(size_t)r * 128 + 64 + lane];
    float p = fmaf(x0, w1[lane], x1 * w1[64 + lane]);
    #pragma unroll
    for (int off = 32; off >= 1; off >>= 1) p += __shfl_xor(p, off, 64);
    if (lane == 0) o1[r] = p + b1[0];
    if (o2 != nullptr) {
        float q = fmaf(x0, w2[lane], x1 * w2[64 + lane]);
        #pragma unroll
        for (int off = 32; off >= 1; off >>= 1) q += __shfl_xor(q, off, 64);
        if (lane == 0) o2[r] = q + b2[0];
    }
}

// ---------------- out-conv scalar attention (block per vnode, max-free) --------
__global__ __launch_bounds__(256) void attn_out(
    const float* __restrict__ qo, const float* __restrict__ ko, const float* __restrict__ vo,
    const int* __restrict__ rowstart, const int* __restrict__ csr,
    const float* __restrict__ arel_o, const float* __restrict__ prel_o,
    const float* __restrict__ mrel_o, const float* __restrict__ Wa_o,
    const float* __restrict__ ba_o, float* __restrict__ outl)
{
    int node = blockIdx.x;
    float qs = qo[node] * arel_o[0] * prel_o[0];
    int rs = rowstart[node], re = rowstart[node + 1];
    float s = 0.f, a = 0.f;
    for (int e = rs + (int)threadIdx.x; e < re; e += 256) {
        int si = csr[e];
        float w = __expf(qs * ko[si]);
        s += w;
        a = fmaf(w, vo[si], a);
    }
    #pragma unroll
    for (int off = 32; off >= 1; off >>= 1) {
        s += __shfl_xor(s, off, 64);
        a += __shfl_xor(a, off, 64);
    }
    __shared__ float sms[4], sma[4];
    int lane = threadIdx.x & 63, wid = threadIdx.x >> 6;
    if (lane == 0) { sms[wid] = s; sma[wid] = a; }
    __syncthreads();
    if (threadIdx.x == 0) {
        float S = sms[0] + sms[1] + sms[2] + sms[3];
        float A = sma[0] + sma[1] + sma[2] + sma[3];
        float agg = (S > 0.f) ? A / S : 0.f;
        agg *= mrel_o[0];
        outl[node] = gelu_tanh(agg) * Wa_o[0] + ba_o[0];
    }
}

// ---------------- final head: JK-max -> node_fc -> MLP ------------------------
__global__ void final_head(const float* __restrict__ outs,
    const float* __restrict__ fc_W, const float* __restrict__ fc_b,
    const float* __restrict__ W1, const float* __restrict__ b1,
    const float* __restrict__ W2, const float* __restrict__ b2,
    float* __restrict__ out)
{
    int b = threadIdx.x;
    if (b >= 64) return;
    float h = fc_b[0];
    #pragma unroll
    for (int v = 0; v < 4; v++) {
        int n = b * 4 + v;
        float jk = fmaxf(fmaxf(outs[0 * N_V + n], outs[1 * N_V + n]), outs[2 * N_V + n]);
        h = fmaf(jk, fc_W[v], h);
    }
    h = gelu_tanh(h);
    float h0 = gelu_tanh(h * W1[0] + b1[0]);
    float h1 = gelu_tanh(h * W1[1] + b1[1]);
    out[b] = h0 * W2[0] + h1 * W2[1] + b2[0];
}

// ---------------- orchestration ----------------------------------------------
extern "C" void kernel_launch(void* const* d_in, const int* in_sizes, int n_in,
                              void* d_out, int out_size, void* d_ws, size_t ws_size,
                              hipStream_t stream) {
    (void)in_sizes; (void)n_in; (void)out_size; (void)ws_size;
    const float* x_cell  = (const float*)d_in[0];
    const float* x_vcell = (const float*)d_in[1];
    const float* Wk   = (const float*)d_in[2];
    const float* bk   = (const float*)d_in[3];
    const float* Wq   = (const float*)d_in[4];
    const float* bq   = (const float*)d_in[5];
    const float* Wv   = (const float*)d_in[6];
    const float* bv   = (const float*)d_in[7];
    const float* Wa   = (const float*)d_in[8];
    const float* ba   = (const float*)d_in[9];
    const float* skip = (const float*)d_in[10];
    const float* arel = (const float*)d_in[11];
    const float* mrel = (const float*)d_in[12];
    const float* prel = (const float*)d_in[13];
    const float* Wk_o = (const float*)d_in[14];
    const float* bk_o = (const float*)d_in[15];
    const float* Wq_o = (const float*)d_in[16];
    const float* bq_o = (const float*)d_in[17];
    const float* Wv_o = (const float*)d_in[18];
    const float* bv_o = (const float*)d_in[19];
    const float* Wa_o = (const float*)d_in[20];
    const float* ba_o = (const float*)d_in[21];
    const float* arel_o = (const float*)d_in[22];
    const float* mrel_o = (const float*)d_in[23];
    const float* prel_o = (const float*)d_in[24];
    const float* fc_W  = (const float*)d_in[25];
    const float* fc_b  = (const float*)d_in[26];
    const float* mlp_W1 = (const float*)d_in[27];
    const float* mlp_b1 = (const float*)d_in[28];
    const float* mlp_W2 = (const float*)d_in[29];
    const float* mlp_b2 = (const float*)d_in[30];
    const int* src_cc = (const int*)d_in[31];
    const int* dst_cc = (const int*)d_in[32];
    const int* src_cv = (const int*)d_in[33];
    const int* dst_cv = (const int*)d_in[34];

    // workspace carve-up (256B aligned)
    char* p = (char*)d_ws;
    auto alloc = [&](size_t bytes) -> char* {
        uintptr_t q = ((uintptr_t)p + 255) & ~(uintptr_t)255;
        p = (char*)(q + bytes);
        return (char*)q;
    };
    float* WQT  = (float*)alloc(sizeof(float) * NL * 2 * CH * CH);
    float* BQT  = (float*)alloc(sizeof(float) * NL * 2 * CH);
    float* XC   = (float*)alloc(sizeof(float) * (size_t)N_C * CH);
    float* XV   = (float*)alloc(sizeof(float) * (size_t)N_V * CH);
    float* XQKV = (float*)alloc(sizeof(float) * (size_t)N_C * 384);  // [q~|k|v] per node
    float* QTV  = (float*)alloc(sizeof(float) * (size_t)N_V * CH);
    float* AGGV = (float*)alloc(sizeof(float) * (size_t)N_V * CH);
    float* KO   = (float*)alloc(sizeof(float) * N_C);
    float* VO   = (float*)alloc(sizeof(float) * N_C);
    float* QO   = (float*)alloc(sizeof(float) * N_V);
    float* OUTS = (float*)alloc(sizeof(float) * NL * N_V);
    // CSR-build scratch
    int* bhist    = (int*)alloc(sizeof(int) * 512);
    int* bhist_cc = bhist;
    int* bhist_cv = bhist + 256;
    int* bbase_cc = (int*)alloc(sizeof(int) * 257);
    int* cur_cc   = (int*)alloc(sizeof(int) * 256);
    int* cur_cv   = (int*)alloc(sizeof(int) * 256);
    int* rs_cc    = (int*)alloc(sizeof(int) * (N_C + 1));
    int* rs_cv    = (int*)alloc(sizeof(int) * (N_V + 1));
    int* csr_cc   = (int*)alloc(sizeof(int) * NE1);
    int* csr_cv   = (int*)alloc(sizeof(int) * NE2);
    int2* tmp_cc  = (int2*)alloc(sizeof(int2) * NE1);

    // ---- setup: composed weights + CSR (two-level counting sort) ----
    compose_wq<<<CDIV(NL * 2 * (CH + 1) * CH, 256), 256, 0, stream>>>(
        Wq, bq, arel, prel, WQT, BQT);
    hipMemsetAsync(bhist, 0, sizeof(int) * 512, stream);
    bucket_hist<<<CDIV(NE1, EPB), 256, 0, stream>>>(dst_cc, NE1, 8, bhist_cc);
    bucket_hist<<<CDIV(NE2, EPB), 256, 0, stream>>>(dst_cv, NE2, 0, bhist_cv);
    scan256<<<1, 256, 0, stream>>>(bhist_cc, bbase_cc, cur_cc);
    scan256<<<1, 256, 0, stream>>>(bhist_cv, rs_cv, cur_cv);   // rs_cv IS the cv row starts
    partition_edges<true ><<<CDIV(NE1, EPB), 256, 0, stream>>>(src_cc, dst_cc, NE1, 8,
                                                               cur_cc, tmp_cc, nullptr);
    partition_edges<false><<<CDIV(NE2, EPB), 256, 0, stream>>>(src_cv, dst_cv, NE2, 0,
                                                               cur_cv, nullptr, csr_cv);
    bucket_finalize<<<CDIV(N_C, 256), 256, 0, stream>>>(tmp_cc, bbase_cc, N_C, NE1,
                                                        rs_cc, csr_cc);

    const int gb_c = CDIV(N_C, 64);
    const int gb_v = CDIV(N_V, 64);

    for (int li = 0; li < NL; li++) {
        const float* xc_src = (li == 0) ? x_cell : XC;
        const float* xv_src = (li == 0) ? x_vcell : XV;
        size_t w0 = (size_t)(li * 2) * CH * CH;
        size_t w1 = (size_t)(li * 2 + 1) * CH * CH;
        int b0 = (li * 2) * CH, b1 = (li * 2 + 1) * CH;

        // fused q~/k/v GEMM -> XQKV[n] = [q~|k|v]; q~v (NV x 128)
        gemm_qkv<<<gb_c, 256, 0, stream>>>(xc_src, 128, N_C,
                                           WQT + w0, Wk + w0, Wv + w0,
                                           BQT + b0, bk + b0, bv + b0, XQKV);
        gemm128<<<gb_v, 256, 0, stream>>>(xv_src, 128, WQT + w1, BQT + b1, QTV, N_V,
                                          nullptr, nullptr);

        // cc attention (max-free, fused mrel+gelu, overwrites q~ slot)
        attn_cc<<<CDIV(N_C, 4), 256, 0, stream>>>(XQKV, rs_cc, csr_cc,
                                                  mrel + (size_t)(li * 2) * NH * HD * HD, N_C);
        // cv attention
        attn_cv<<<N_V, 1024, 0, stream>>>(QTV, XQKV, rs_cv, csr_cv,
                                          mrel + (size_t)(li * 2 + 1) * NH * HD * HD, AGGV);

        // Wa GEMMs with skip epilogue
        gemm128<<<gb_c, 256, 0, stream>>>(XQKV, 384, Wa + w0, ba + b0, XC, N_C,
                                          skip + li * 2, xc_src);
        gemm128<<<gb_v, 256, 0, stream>>>(AGGV, 128, Wa + w1, ba + b1, XV, N_V,
                                          skip + li * 2 + 1, xv_src);

        // out-conv: scalar attention on cv edges
        proj2<<<CDIV(N_C, 4), 256, 0, stream>>>(XC, N_C, Wk_o + li * CH, bk_o + li, KO,
                                                Wv_o + li * CH, bv_o + li, VO);
        proj2<<<CDIV(N_V, 4), 256, 0, stream>>>(XV, N_V, Wq_o + li * CH, bq_o + li, QO,
                                                nullptr, nullptr, nullptr);
        attn_out<<<N_V, 256, 0, stream>>>(QO, KO, VO, rs_cv, csr_cv,
                                          arel_o + li, prel_o + li, mrel_o + li,
                                          Wa_o + li, ba_o + li, OUTS + li * N_V);
    }

    final_head<<<1, 64, 0, stream>>>(OUTS, fc_W, fc_b, mlp_W1, mlp_b1, mlp_W2, mlp_b2,
                                     (float*)d_out);
}

// Round 4
// 1247.416 us; speedup vs baseline: 1.4159x; 1.1426x over previous
//
#include <hip/hip_runtime.h>
#include <math.h>
#include <stdint.h>

#define N_C 60000
#define N_V 256
#define CH 128
#define NH 4
#define HD 32
#define NL 3
#define NE1 600000
#define NE2 240000

#define CDIV(a,b) (((a)+(b)-1)/(b))
#define EPB 4096   // edges per block in CSR-build kernels

__device__ __forceinline__ float gelu_tanh(float x) {
    float x3 = x * x * x;
    float t = tanhf(0.7978845608028654f * (x + 0.044715f * x3));
    return 0.5f * x * (1.0f + t);
}

__device__ __forceinline__ float dot8(float4 qa, float4 qb, float4 ka, float4 kb) {
    float d = qa.x * ka.x;
    d = fmaf(qa.y, ka.y, d);
    d = fmaf(qa.z, ka.z, d);
    d = fmaf(qa.w, ka.w, d);
    d = fmaf(qb.x, kb.x, d);
    d = fmaf(qb.y, kb.y, d);
    d = fmaf(qb.z, kb.z, d);
    d = fmaf(qb.w, kb.w, d);
    return d;
}

// ---------------- weight composition: W~q = Wq . arel  (prel/sqrt(D) folded) ---
__global__ __launch_bounds__(256) void compose_wq(
    const float* __restrict__ Wq, const float* __restrict__ bq,
    const float* __restrict__ arel, const float* __restrict__ prel,
    float* __restrict__ WQT, float* __restrict__ BQT)
{
    int gid = blockIdx.x * blockDim.x + threadIdx.x;
    const int total = NL * 2 * (CH + 1) * CH;
    if (gid >= total) return;
    int li2 = gid / ((CH + 1) * CH);
    int rem = gid % ((CH + 1) * CH);
    int c   = rem / CH;          // 0..CH ; CH => bias row
    int col = rem % CH;
    int h = col >> 5, d = col & 31;
    const float* ar = arel + (li2 * NH + h) * (HD * HD) + d * HD;  // [e]
    float scale = prel[li2 * NH + h] * 0.17677669529663687f;       // prel/sqrt(32)
    const float* src = (c < CH) ? (Wq + ((size_t)li2 * CH + c) * CH + h * HD)
                                : (bq + li2 * CH + h * HD);
    float acc = 0.f;
    #pragma unroll
    for (int e = 0; e < HD; e++) acc = fmaf(src[e], ar[e], acc);
    acc *= scale;
    if (c < CH) WQT[((size_t)li2 * CH + c) * CH + col] = acc;
    else        BQT[li2 * CH + col] = acc;
}

// ================= CSR build: two-level LDS counting sort =====================
__global__ __launch_bounds__(256) void bucket_hist(const int* __restrict__ dst, int E,
                                                   int shift, int* __restrict__ bhist)
{
    __shared__ int h[256];
    int t = threadIdx.x;
    h[t] = 0;
    __syncthreads();
    int i0 = blockIdx.x * EPB, i1 = min(i0 + EPB, E);
    for (int i = i0 + t; i < i1; i += 256)
        atomicAdd(&h[(dst[i] >> shift) & 255], 1);
    __syncthreads();
    if (h[t] > 0) atomicAdd(&bhist[t], h[t]);
}

__global__ __launch_bounds__(256) void scan256(const int* __restrict__ h,
                                               int* __restrict__ base, int* __restrict__ cur)
{
    __shared__ int p[256];
    int t = threadIdx.x;
    int v = h[t];
    p[t] = v;
    __syncthreads();
    for (int off = 1; off < 256; off <<= 1) {
        int u = (t >= off) ? p[t - off] : 0;
        __syncthreads();
        p[t] += u;
        __syncthreads();
    }
    base[t] = p[t] - v;
    cur[t]  = p[t] - v;
    if (t == 255) base[256] = p[255];
}

template<bool PAIR>
__global__ __launch_bounds__(256) void partition_edges(
    const int* __restrict__ src, const int* __restrict__ dst, int E, int shift,
    int* __restrict__ cur, int2* __restrict__ tmp_pair, int* __restrict__ out_src)
{
    __shared__ int cnt[256], base[256], cnt2[256];
    int t = threadIdx.x;
    cnt[t] = 0; cnt2[t] = 0;
    __syncthreads();
    int i0 = blockIdx.x * EPB, i1 = min(i0 + EPB, E);
    for (int i = i0 + t; i < i1; i += 256)
        atomicAdd(&cnt[(dst[i] >> shift) & 255], 1);
    __syncthreads();
    if (cnt[t] > 0) base[t] = atomicAdd(&cur[t], cnt[t]);
    __syncthreads();
    for (int i = i0 + t; i < i1; i += 256) {
        int d = dst[i];
        int dig = (d >> shift) & 255;
        int r = atomicAdd(&cnt2[dig], 1);
        int pos = base[dig] + r;
        if constexpr (PAIR) tmp_pair[pos] = make_int2(src[i], d);
        else                out_src[pos] = src[i];
    }
}

__global__ __launch_bounds__(256) void bucket_finalize(
    const int2* __restrict__ tmp, const int* __restrict__ bbase, int n, int NE,
    int* __restrict__ rs, int* __restrict__ csr)
{
    __shared__ int cnt[256], pre[256], cnt2[256];
    int b = blockIdx.x, t = threadIdx.x;
    int s0 = bbase[b], s1 = bbase[b + 1];
    cnt[t] = 0; cnt2[t] = 0;
    __syncthreads();
    for (int i = s0 + t; i < s1; i += 256)
        atomicAdd(&cnt[tmp[i].y & 255], 1);
    __syncthreads();
    int v = cnt[t];
    pre[t] = v;
    __syncthreads();
    for (int off = 1; off < 256; off <<= 1) {
        int u = (t >= off) ? pre[t - off] : 0;
        __syncthreads();
        pre[t] += u;
        __syncthreads();
    }
    pre[t] -= v;   // exclusive
    __syncthreads();
    int dstid = b * 256 + t;
    if (dstid < n) rs[dstid] = s0 + pre[t];
    if (b == 0 && t == 0) rs[n] = NE;
    for (int i = s0 + t; i < s1; i += 256) {
        int2 e = tmp[i];
        int low = e.y & 255;
        int r = atomicAdd(&cnt2[low], 1);
        csr[s0 + pre[low] + r] = e.x;
    }
}

// ---------------- fused q~/k/v GEMM: A[M,128] x 3 weights -> out[M,384] --------
__global__ __launch_bounds__(256) void gemm_qkv(
    const float* __restrict__ A, int lda, int M,
    const float* __restrict__ W0, const float* __restrict__ W1, const float* __restrict__ W2,
    const float* __restrict__ b0, const float* __restrict__ b1, const float* __restrict__ b2,
    float* __restrict__ out)
{
    __shared__ float As[128][64];   // [k][r] 32 KB
    __shared__ float Bs[32][128];   // 16 KB
    int tid = threadIdx.x;
    int row0 = blockIdx.x * 64;
    int tx = tid & 31;   // cols tx*4..+3
    int ty = tid >> 5;   // rows ty*8..+7
    #pragma unroll
    for (int i = 0; i < 8; i++) {
        int slot = tid + i * 256;            // [0,2048) float4 slots
        int r = slot >> 5, kq = slot & 31;
        int rr = row0 + r;
        float4 v = make_float4(0.f, 0.f, 0.f, 0.f);
        if (rr < M) v = *(const float4*)(A + (size_t)rr * lda + kq * 4);
        As[kq * 4 + 0][r] = v.x; As[kq * 4 + 1][r] = v.y;
        As[kq * 4 + 2][r] = v.z; As[kq * 4 + 3][r] = v.w;
    }
    const float* Ws[3] = {W0, W1, W2};
    const float* bs[3] = {b0, b1, b2};
    for (int jw = 0; jw < 3; jw++) {
        float acc[8][4] = {};
        for (int k0 = 0; k0 < 128; k0 += 32) {
            __syncthreads();
            #pragma unroll
            for (int i = 0; i < 4; i++) {
                int slot = tid + i * 256;    // [0,1024)
                int kr = slot >> 5, cq = slot & 31;
                *(float4*)&Bs[kr][cq * 4] = *(const float4*)(Ws[jw] + (size_t)(k0 + kr) * 128 + cq * 4);
            }
            __syncthreads();
            #pragma unroll
            for (int k = 0; k < 32; k++) {
                float a[8], b[4];
                #pragma unroll
                for (int i = 0; i < 8; i++) a[i] = As[k0 + k][ty * 8 + i];
                #pragma unroll
                for (int j = 0; j < 4; j++) b[j] = Bs[k][tx * 4 + j];
                #pragma unroll
                for (int i = 0; i < 8; i++)
                    #pragma unroll
                    for (int j = 0; j < 4; j++) acc[i][j] = fmaf(a[i], b[j], acc[i][j]);
            }
        }
        #pragma unroll
        for (int i = 0; i < 8; i++) {
            int r = row0 + ty * 8 + i;
            if (r >= M) continue;
            #pragma unroll
            for (int j = 0; j < 4; j++) {
                int c = tx * 4 + j;
                out[(size_t)r * 384 + jw * 128 + c] = acc[i][j] + bs[jw][c];
            }
        }
    }
}

// ---------------- fp32 GEMM: out[M,128] = A[M,lda-strided,128] @ W + bias ------
__global__ __launch_bounds__(256) void gemm128(
    const float* __restrict__ A, int lda, const float* __restrict__ W,
    const float* __restrict__ bias, float* out, int M,
    const float* __restrict__ gate, const float* xold)
{
    __shared__ float As[32][64];
    __shared__ float Bs[32][128];
    int tid = threadIdx.x;
    int row0 = blockIdx.x * 64;
    int tx = tid & 31;
    int ty = tid >> 5;
    float acc[8][4] = {};
    for (int k0 = 0; k0 < 128; k0 += 32) {
        #pragma unroll
        for (int i = 0; i < 2; i++) {
            int slot = tid + i * 256;            // [0,512)
            int r = slot >> 3, kq = slot & 7;
            int rr = row0 + r;
            float4 v = make_float4(0.f, 0.f, 0.f, 0.f);
            if (rr < M) v = *(const float4*)(A + (size_t)rr * lda + k0 + kq * 4);
            As[kq * 4 + 0][r] = v.x; As[kq * 4 + 1][r] = v.y;
            As[kq * 4 + 2][r] = v.z; As[kq * 4 + 3][r] = v.w;
        }
        #pragma unroll
        for (int i = 0; i < 4; i++) {
            int slot = tid + i * 256;            // [0,1024)
            int kr = slot >> 5, cq = slot & 31;
            float4 v = *(const float4*)(W + (size_t)(k0 + kr) * 128 + cq * 4);
            *(float4*)&Bs[kr][cq * 4] = v;
        }
        __syncthreads();
        #pragma unroll
        for (int k = 0; k < 32; k++) {
            float a[8], b[4];
            #pragma unroll
            for (int i = 0; i < 8; i++) a[i] = As[k][ty * 8 + i];
            #pragma unroll
            for (int j = 0; j < 4; j++) b[j] = Bs[k][tx * 4 + j];
            #pragma unroll
            for (int i = 0; i < 8; i++)
                #pragma unroll
                for (int j = 0; j < 4; j++) acc[i][j] = fmaf(a[i], b[j], acc[i][j]);
        }
        __syncthreads();
    }
    float g = 1.f, og = 0.f;
    if (gate != nullptr) { g = 1.f / (1.f + expf(-gate[0])); og = 1.f - g; }
    #pragma unroll
    for (int i = 0; i < 8; i++) {
        int r = row0 + ty * 8 + i;
        if (r >= M) continue;
        #pragma unroll
        for (int j = 0; j < 4; j++) {
            int c = tx * 4 + j;
            float v = acc[i][j] + bias[c];
            if (gate != nullptr) v = g * v + og * xold[(size_t)r * 128 + c];
            out[(size_t)r * 128 + c] = v;
        }
    }
}

// ---------------- group-of-16 edge accumulation (4 edges in flight + 2x unroll)
// lane = 16*g + j; lane holds channels [8j, 8j+8). Edge set for group g:
// {base+g, base+g+4, ...} within [e0,e1). Per-head dot = 2 shfl (4-lane cluster).
// Max-free softmax: s = sum exp(logit), acc = sum exp(logit)*v (associative).
__device__ __forceinline__ void accum_g16(
    const float* __restrict__ xqkv, const int* __restrict__ csr,
    int e0, int e1, int g, float4 qa, float4 qb, float& s_io, float acc[8])
{
    float s = 0.f;
    int e = e0 + g;
    for (; e + 4 < e1; e += 8) {
        int i0 = csr[e], i1 = csr[e + 4];
        const float* p0 = xqkv + (size_t)i0 * 384 + 128 + ((threadIdx.x & 15) * 8);
        const float* p1 = xqkv + (size_t)i1 * 384 + 128 + ((threadIdx.x & 15) * 8);
        float4 k0a = *(const float4*)p0,         k0b = *(const float4*)(p0 + 4);
        float4 v0a = *(const float4*)(p0 + 128), v0b = *(const float4*)(p0 + 132);
        float4 k1a = *(const float4*)p1,         k1b = *(const float4*)(p1 + 4);
        float4 v1a = *(const float4*)(p1 + 128), v1b = *(const float4*)(p1 + 132);
        float d0 = dot8(qa, qb, k0a, k0b);
        float d1 = dot8(qa, qb, k1a, k1b);
        d0 += __shfl_xor(d0, 1, 64); d1 += __shfl_xor(d1, 1, 64);
        d0 += __shfl_xor(d0, 2, 64); d1 += __shfl_xor(d1, 2, 64);
        float w0 = __expf(d0), w1 = __expf(d1);
        s += w0 + w1;
        acc[0] = fmaf(w0, v0a.x, acc[0]); acc[0] = fmaf(w1, v1a.x, acc[0]);
        acc[1] = fmaf(w0, v0a.y, acc[1]); acc[1] = fmaf(w1, v1a.y, acc[1]);
        acc[2] = fmaf(w0, v0a.z, acc[2]); acc[2] = fmaf(w1, v1a.z, acc[2]);
        acc[3] = fmaf(w0, v0a.w, acc[3]); acc[3] = fmaf(w1, v1a.w, acc[3]);
        acc[4] = fmaf(w0, v0b.x, acc[4]); acc[4] = fmaf(w1, v1b.x, acc[4]);
        acc[5] = fmaf(w0, v0b.y, acc[5]); acc[5] = fmaf(w1, v1b.y, acc[5]);
        acc[6] = fmaf(w0, v0b.z, acc[6]); acc[6] = fmaf(w1, v1b.z, acc[6]);
        acc[7] = fmaf(w0, v0b.w, acc[7]); acc[7] = fmaf(w1, v1b.w, acc[7]);
    }
    if (e < e1) {
        int i0 = csr[e];
        const float* p0 = xqkv + (size_t)i0 * 384 + 128 + ((threadIdx.x & 15) * 8);
        float4 k0a = *(const float4*)p0,         k0b = *(const float4*)(p0 + 4);
        float4 v0a = *(const float4*)(p0 + 128), v0b = *(const float4*)(p0 + 132);
        float d0 = dot8(qa, qb, k0a, k0b);
        d0 += __shfl_xor(d0, 1, 64);
        d0 += __shfl_xor(d0, 2, 64);
        float w0 = __expf(d0);
        s += w0;
        acc[0] = fmaf(w0, v0a.x, acc[0]);
        acc[1] = fmaf(w0, v0a.y, acc[1]);
        acc[2] = fmaf(w0, v0a.z, acc[2]);
        acc[3] = fmaf(w0, v0a.w, acc[3]);
        acc[4] = fmaf(w0, v0b.x, acc[4]);
        acc[5] = fmaf(w0, v0b.y, acc[5]);
        acc[6] = fmaf(w0, v0b.z, acc[6]);
        acc[7] = fmaf(w0, v0b.w, acc[7]);
    }
    s_io = s;
}

// ---------------- cc attention: wave/node, NO block barrier, fused mrel+gelu ---
// LDS rowbuf padded +4 per head (offset c + 4*(c>>5)) -> bank-conflict-free.
__global__ __launch_bounds__(256) void attn_cc(
    float* xqkv, const int* __restrict__ rowstart, const int* __restrict__ csr,
    const float* __restrict__ mrel, int n)
{
    __shared__ float rowbuf[4][144];
    int lane = threadIdx.x & 63, wid = threadIdx.x >> 6;
    int node = blockIdx.x * 4 + wid;
    if (node >= n) return;
    int g = lane >> 4, j = lane & 15;
    const float* qp = xqkv + (size_t)node * 384 + 8 * j;
    float4 qa = *(const float4*)qp, qb = *(const float4*)(qp + 4);
    int rs = rowstart[node], re = rowstart[node + 1];
    float s = 0.f;
    float acc[8] = {};
    accum_g16(xqkv, csr, rs, re, g, qa, qb, s, acc);
    // merge the 4 groups (wave-internal)
    #pragma unroll
    for (int i = 0; i < 8; i++) {
        acc[i] += __shfl_xor(acc[i], 16, 64);
        acc[i] += __shfl_xor(acc[i], 32, 64);
    }
    s += __shfl_xor(s, 16, 64);
    s += __shfl_xor(s, 32, 64);
    float inv = (s > 0.f) ? 1.f / s : 0.f;
    if (g == 0) {
        int off = 8 * j + 4 * (j >> 2);   // +4 pad per head
        float4 o0 = make_float4(acc[0] * inv, acc[1] * inv, acc[2] * inv, acc[3] * inv);
        float4 o1 = make_float4(acc[4] * inv, acc[5] * inv, acc[6] * inv, acc[7] * inv);
        *(float4*)&rowbuf[wid][off]     = o0;
        *(float4*)&rowbuf[wid][off + 4] = o1;
    }
    // intra-wave DS ordering guarantees visibility; no __syncthreads needed
    int lp = 2 * lane;
    int h = lp >> 5, eo = lp & 31;
    const float* mr = mrel + h * 1024 + eo;
    const float* rb = rowbuf[wid] + 36 * h;
    float t0 = 0.f, t1 = 0.f;
    #pragma unroll
    for (int d = 0; d < 32; d++) {
        float a = rb[d];
        t0 = fmaf(a, mr[d * 32], t0);
        t1 = fmaf(a, mr[d * 32 + 1], t1);
    }
    float2 o = make_float2(gelu_tanh(t0), gelu_tanh(t1));
    *(float2*)(xqkv + (size_t)node * 384 + lp) = o;
}

// ---------------- cv attention: block/node (16 waves x 4 groups), fused --------
__global__ __launch_bounds__(1024) void attn_cv(
    const float* __restrict__ qtv, const float* __restrict__ xqkv,
    const int* __restrict__ rowstart, const int* __restrict__ csr,
    const float* __restrict__ mrel, float* __restrict__ aggv)
{
    __shared__ float sm_s[16][4];
    __shared__ float sm_a[16][128];
    __shared__ float orow[144];
    int lane = threadIdx.x & 63, w = threadIdx.x >> 6;
    int node = blockIdx.x;
    int g = lane >> 4, j = lane & 15;
    const float* qp = qtv + (size_t)node * 128 + 8 * j;
    float4 qa = *(const float4*)qp, qb = *(const float4*)(qp + 4);
    int rs = rowstart[node], re = rowstart[node + 1];
    int cnt = re - rs;
    int per = (cnt + 15) >> 4;
    int e0 = rs + w * per, e1 = min(e0 + per, re);
    float s = 0.f;
    float acc[8] = {};
    accum_g16(xqkv, csr, e0, e1, g, qa, qb, s, acc);
    #pragma unroll
    for (int i = 0; i < 8; i++) {
        acc[i] += __shfl_xor(acc[i], 16, 64);
        acc[i] += __shfl_xor(acc[i], 32, 64);
    }
    s += __shfl_xor(s, 16, 64);
    s += __shfl_xor(s, 32, 64);
    if (g == 0) {
        *(float4*)&sm_a[w][8 * j]     = make_float4(acc[0], acc[1], acc[2], acc[3]);
        *(float4*)&sm_a[w][8 * j + 4] = make_float4(acc[4], acc[5], acc[6], acc[7]);
        if ((j & 3) == 0) sm_s[w][j >> 2] = s;
    }
    __syncthreads();
    if (threadIdx.x < 64) {
        int lp = 2 * lane;
        int h = lp >> 5;
        float S = 0.f, AX = 0.f, AY = 0.f;
        #pragma unroll
        for (int i = 0; i < 16; i++) {
            S  += sm_s[i][h];
            float2 a2 = *(const float2*)&sm_a[i][lp];
            AX += a2.x;
            AY += a2.y;
        }
        float inv = (S > 0.f) ? 1.f / S : 0.f;
        int off = lp + 4 * h;   // padded
        orow[off]     = AX * inv;
        orow[off + 1] = AY * inv;
        // wave-0 internal ordering: no barrier needed
        int eo = lp & 31;
        const float* mr = mrel + h * 1024 + eo;
        const float* rb = orow + 36 * h;
        float t0 = 0.f, t1 = 0.f;
        #pragma unroll
        for (int d = 0; d < 32; d++) {
            float a = rb[d];
            t0 = fmaf(a, mr[d * 32], t0);
            t1 = fmaf(a, mr[d * 32 + 1], t1);
        }
        aggv[(size_t)node * 128 + lp]     = gelu_tanh(t0);
        aggv[(size_t)node * 128 + lp + 1] = gelu_tanh(t1);
    }
}

// ---------------- out-conv projections (C -> 1), wave per row -----------------
__global__ __launch_bounds__(256) void proj2(const float* __restrict__ x, int n,
    const float* __restrict__ w1, const float* __restrict__ b1, float* __restrict__ o1,
    const float* __restrict__ w2, const float* __restrict__ b2, float* __restrict__ o2)
{
    int lane = threadIdx.x & 63;
    int wid = threadIdx.x >> 6;
    int r = blockIdx.x * 4 + wid;
    if (r >= n) return;
    float x0 = x[(size_t)r * 128 + lane], x1 = x[(size_t)r * 128 + 64 + lane];
    float p = fmaf(x0, w1[lane], x1 * w1[64 + lane]);
    #pragma unroll
    for (int off = 32; off >= 1; off >>= 1) p += __shfl_xor(p, off, 64);
    if (lane == 0) o1[r] = p + b1[0];
    if (o2 != nullptr) {
        float q = fmaf(x0, w2[lane], x1 * w2[64 + lane]);
        #pragma unroll
        for (int off = 32; off >= 1; off >>= 1) q += __shfl_xor(q, off, 64);
        if (lane == 0) o2[r] = q + b2[0];
    }
}

// ---------------- out-conv scalar attention (block per vnode, max-free) --------
__global__ __launch_bounds__(256) void attn_out(
    const float* __restrict__ qo, const float* __restrict__ ko, const float* __restrict__ vo,
    const int* __restrict__ rowstart, const int* __restrict__ csr,
    const float* __restrict__ arel_o, const float* __restrict__ prel_o,
    const float* __restrict__ mrel_o, const float* __restrict__ Wa_o,
    const float* __restrict__ ba_o, float* __restrict__ outl)
{
    int node = blockIdx.x;
    float qs = qo[node] * arel_o[0] * prel_o[0];
    int rs = rowstart[node], re = rowstart[node + 1];
    float s = 0.f, a = 0.f;
    for (int e = rs + (int)threadIdx.x; e < re; e += 256) {
        int si = csr[e];
        float w = __expf(qs * ko[si]);
        s += w;
        a = fmaf(w, vo[si], a);
    }
    #pragma unroll
    for (int off = 32; off >= 1; off >>= 1) {
        s += __shfl_xor(s, off, 64);
        a += __shfl_xor(a, off, 64);
    }
    __shared__ float sms[4], sma[4];
    int lane = threadIdx.x & 63, wid = threadIdx.x >> 6;
    if (lane == 0) { sms[wid] = s; sma[wid] = a; }
    __syncthreads();
    if (threadIdx.x == 0) {
        float S = sms[0] + sms[1] + sms[2] + sms[3];
        float A = sma[0] + sma[1] + sma[2] + sma[3];
        float agg = (S > 0.f) ? A / S : 0.f;
        agg *= mrel_o[0];
        outl[node] = gelu_tanh(agg) * Wa_o[0] + ba_o[0];
    }
}

// ---------------- final head: JK-max -> node_fc -> MLP ------------------------
__global__ void final_head(const float* __restrict__ outs,
    const float* __restrict__ fc_W, const float* __restrict__ fc_b,
    const float* __restrict__ W1, const float* __restrict__ b1,
    const float* __restrict__ W2, const float* __restrict__ b2,
    float* __restrict__ out)
{
    int b = threadIdx.x;
    if (b >= 64) return;
    float h = fc_b[0];
    #pragma unroll
    for (int v = 0; v < 4; v++) {
        int n = b * 4 + v;
        float jk = fmaxf(fmaxf(outs[0 * N_V + n], outs[1 * N_V + n]), outs[2 * N_V + n]);
        h = fmaf(jk, fc_W[v], h);
    }
    h = gelu_tanh(h);
    float h0 = gelu_tanh(h * W1[0] + b1[0]);
    float h1 = gelu_tanh(h * W1[1] + b1[1]);
    out[b] = h0 * W2[0] + h1 * W2[1] + b2[0];
}

// ---------------- orchestration ----------------------------------------------
extern "C" void kernel_launch(void* const* d_in, const int* in_sizes, int n_in,
                              void* d_out, int out_size, void* d_ws, size_t ws_size,
                              hipStream_t stream) {
    (void)in_sizes; (void)n_in; (void)out_size; (void)ws_size;
    const float* x_cell  = (const float*)d_in[0];
    const float* x_vcell = (const float*)d_in[1];
    const float* Wk   = (const float*)d_in[2];
    const float* bk   = (const float*)d_in[3];
    const float* Wq   = (const float*)d_in[4];
    const float* bq   = (const float*)d_in[5];
    const float* Wv   = (const float*)d_in[6];
    const float* bv   = (const float*)d_in[7];
    const float* Wa   = (const float*)d_in[8];
    const float* ba   = (const float*)d_in[9];
    const float* skip = (const float*)d_in[10];
    const float* arel = (const float*)d_in[11];
    const float* mrel = (const float*)d_in[12];
    const float* prel = (const float*)d_in[13];
    const float* Wk_o = (const float*)d_in[14];
    const float* bk_o = (const float*)d_in[15];
    const float* Wq_o = (const float*)d_in[16];
    const float* bq_o = (const float*)d_in[17];
    const float* Wv_o = (const float*)d_in[18];
    const float* bv_o = (const float*)d_in[19];
    const float* Wa_o = (const float*)d_in[20];
    const float* ba_o = (const float*)d_in[21];
    const float* arel_o = (const float*)d_in[22];
    const float* mrel_o = (const float*)d_in[23];
    const float* prel_o = (const float*)d_in[24];
    const float* fc_W  = (const float*)d_in[25];
    const float* fc_b  = (const float*)d_in[26];
    const float* mlp_W1 = (const float*)d_in[27];
    const float* mlp_b1 = (const float*)d_in[28];
    const float* mlp_W2 = (const float*)d_in[29];
    const float* mlp_b2 = (const float*)d_in[30];
    const int* src_cc = (const int*)d_in[31];
    const int* dst_cc = (const int*)d_in[32];
    const int* src_cv = (const int*)d_in[33];
    const int* dst_cv = (const int*)d_in[34];

    // workspace carve-up (256B aligned)
    char* p = (char*)d_ws;
    auto alloc = [&](size_t bytes) -> char* {
        uintptr_t q = ((uintptr_t)p + 255) & ~(uintptr_t)255;
        p = (char*)(q + bytes);
        return (char*)q;
    };
    float* WQT  = (float*)alloc(sizeof(float) * NL * 2 * CH * CH);
    float* BQT  = (float*)alloc(sizeof(float) * NL * 2 * CH);
    float* XC   = (float*)alloc(sizeof(float) * (size_t)N_C * CH);
    float* XV   = (float*)alloc(sizeof(float) * (size_t)N_V * CH);
    float* XQKV = (float*)alloc(sizeof(float) * (size_t)N_C * 384);  // [q~|k|v] per node
    float* QTV  = (float*)alloc(sizeof(float) * (size_t)N_V * CH);
    float* AGGV = (float*)alloc(sizeof(float) * (size_t)N_V * CH);
    float* KO   = (float*)alloc(sizeof(float) * N_C);
    float* VO   = (float*)alloc(sizeof(float) * N_C);
    float* QO   = (float*)alloc(sizeof(float) * N_V);
    float* OUTS = (float*)alloc(sizeof(float) * NL * N_V);
    // CSR-build scratch
    int* bhist    = (int*)alloc(sizeof(int) * 512);
    int* bhist_cc = bhist;
    int* bhist_cv = bhist + 256;
    int* bbase_cc = (int*)alloc(sizeof(int) * 257);
    int* cur_cc   = (int*)alloc(sizeof(int) * 256);
    int* cur_cv   = (int*)alloc(sizeof(int) * 256);
    int* rs_cc    = (int*)alloc(sizeof(int) * (N_C + 1));
    int* rs_cv    = (int*)alloc(sizeof(int) * (N_V + 1));
    int* csr_cc   = (int*)alloc(sizeof(int) * NE1);
    int* csr_cv   = (int*)alloc(sizeof(int) * NE2);
    int2* tmp_cc  = (int2*)alloc(sizeof(int2) * NE1);

    // ---- setup: composed weights + CSR (two-level counting sort) ----
    compose_wq<<<CDIV(NL * 2 * (CH + 1) * CH, 256), 256, 0, stream>>>(
        Wq, bq, arel, prel, WQT, BQT);
    hipMemsetAsync(bhist, 0, sizeof(int) * 512, stream);
    bucket_hist<<<CDIV(NE1, EPB), 256, 0, stream>>>(dst_cc, NE1, 8, bhist_cc);
    bucket_hist<<<CDIV(NE2, EPB), 256, 0, stream>>>(dst_cv, NE2, 0, bhist_cv);
    scan256<<<1, 256, 0, stream>>>(bhist_cc, bbase_cc, cur_cc);
    scan256<<<1, 256, 0, stream>>>(bhist_cv, rs_cv, cur_cv);   // rs_cv IS the cv row starts
    partition_edges<true ><<<CDIV(NE1, EPB), 256, 0, stream>>>(src_cc, dst_cc, NE1, 8,
                                                               cur_cc, tmp_cc, nullptr);
    partition_edges<false><<<CDIV(NE2, EPB), 256, 0, stream>>>(src_cv, dst_cv, NE2, 0,
                                                               cur_cv, nullptr, csr_cv);
    bucket_finalize<<<CDIV(N_C, 256), 256, 0, stream>>>(tmp_cc, bbase_cc, N_C, NE1,
                                                        rs_cc, csr_cc);

    const int gb_c = CDIV(N_C, 64);
    const int gb_v = CDIV(N_V, 64);

    for (int li = 0; li < NL; li++) {
        const float* xc_src = (li == 0) ? x_cell : XC;
        const float* xv_src = (li == 0) ? x_vcell : XV;
        size_t w0 = (size_t)(li * 2) * CH * CH;
        size_t w1 = (size_t)(li * 2 + 1) * CH * CH;
        int b0 = (li * 2) * CH, b1 = (li * 2 + 1) * CH;

        // fused q~/k/v GEMM -> XQKV[n] = [q~|k|v]; q~v (NV x 128)
        gemm_qkv<<<gb_c, 256, 0, stream>>>(xc_src, 128, N_C,
                                           WQT + w0, Wk + w0, Wv + w0,
                                           BQT + b0, bk + b0, bv + b0, XQKV);
        gemm128<<<gb_v, 256, 0, stream>>>(xv_src, 128, WQT + w1, BQT + b1, QTV, N_V,
                                          nullptr, nullptr);

        // cc attention (max-free, group-of-16, fused mrel+gelu, in-place q~ slot)
        attn_cc<<<CDIV(N_C, 4), 256, 0, stream>>>(XQKV, rs_cc, csr_cc,
                                                  mrel + (size_t)(li * 2) * NH * HD * HD, N_C);
        // cv attention
        attn_cv<<<N_V, 1024, 0, stream>>>(QTV, XQKV, rs_cv, csr_cv,
                                          mrel + (size_t)(li * 2 + 1) * NH * HD * HD, AGGV);

        // Wa GEMMs with skip epilogue
        gemm128<<<gb_c, 256, 0, stream>>>(XQKV, 384, Wa + w0, ba + b0, XC, N_C,
                                          skip + li * 2, xc_src);
        gemm128<<<gb_v, 256, 0, stream>>>(AGGV, 128, Wa + w1, ba + b1, XV, N_V,
                                          skip + li * 2 + 1, xv_src);

        // out-conv: scalar attention on cv edges
        proj2<<<CDIV(N_C, 4), 256, 0, stream>>>(XC, N_C, Wk_o + li * CH, bk_o + li, KO,
                                                Wv_o + li * CH, bv_o + li, VO);
        proj2<<<CDIV(N_V, 4), 256, 0, stream>>>(XV, N_V, Wq_o + li * CH, bq_o + li, QO,
                                                nullptr, nullptr, nullptr);
        attn_out<<<N_V, 256, 0, stream>>>(QO, KO, VO, rs_cv, csr_cv,
                                          arel_o + li, prel_o + li, mrel_o + li,
                                          Wa_o + li, ba_o + li, OUTS + li * N_V);
    }

    final_head<<<1, 64, 0, stream>>>(OUTS, fc_W, fc_b, mlp_W1, mlp_b1, mlp_W2, mlp_b2,
                                     (float*)d_out);
}

// Round 5
// 1227.793 us; speedup vs baseline: 1.4385x; 1.0160x over previous
//
#include <hip/hip_runtime.h>
#include <math.h>
#include <stdint.h>

#define N_C 60000
#define N_V 256
#define CH 128
#define NH 4
#define HD 32
#define NL 3
#define NE1 600000
#define NE2 240000

#define CDIV(a,b) (((a)+(b)-1)/(b))
#define EPB 4096   // edges per block in CSR-build kernels

__device__ __forceinline__ float gelu_tanh(float x) {
    float x3 = x * x * x;
    float t = tanhf(0.7978845608028654f * (x + 0.044715f * x3));
    return 0.5f * x * (1.0f + t);
}

__device__ __forceinline__ float dot8(float4 qa, float4 qb, float4 ka, float4 kb) {
    float d = qa.x * ka.x;
    d = fmaf(qa.y, ka.y, d);
    d = fmaf(qa.z, ka.z, d);
    d = fmaf(qa.w, ka.w, d);
    d = fmaf(qb.x, kb.x, d);
    d = fmaf(qb.y, kb.y, d);
    d = fmaf(qb.z, kb.z, d);
    d = fmaf(qb.w, kb.w, d);
    return d;
}

// ---------------- weight composition: W~q = Wq . arel  (prel/sqrt(D) folded) ---
__global__ __launch_bounds__(256) void compose_wq(
    const float* __restrict__ Wq, const float* __restrict__ bq,
    const float* __restrict__ arel, const float* __restrict__ prel,
    float* __restrict__ WQT, float* __restrict__ BQT)
{
    int gid = blockIdx.x * blockDim.x + threadIdx.x;
    const int total = NL * 2 * (CH + 1) * CH;
    if (gid >= total) return;
    int li2 = gid / ((CH + 1) * CH);
    int rem = gid % ((CH + 1) * CH);
    int c   = rem / CH;          // 0..CH ; CH => bias row
    int col = rem % CH;
    int h = col >> 5, d = col & 31;
    const float* ar = arel + (li2 * NH + h) * (HD * HD) + d * HD;  // [e]
    float scale = prel[li2 * NH + h] * 0.17677669529663687f;       // prel/sqrt(32)
    const float* src = (c < CH) ? (Wq + ((size_t)li2 * CH + c) * CH + h * HD)
                                : (bq + li2 * CH + h * HD);
    float acc = 0.f;
    #pragma unroll
    for (int e = 0; e < HD; e++) acc = fmaf(src[e], ar[e], acc);
    acc *= scale;
    if (c < CH) WQT[((size_t)li2 * CH + c) * CH + col] = acc;
    else        BQT[li2 * CH + col] = acc;
}

// ================= CSR build: two-level LDS counting sort =====================
__global__ __launch_bounds__(256) void bucket_hist(const int* __restrict__ dst, int E,
                                                   int shift, int* __restrict__ bhist)
{
    __shared__ int h[256];
    int t = threadIdx.x;
    h[t] = 0;
    __syncthreads();
    int i0 = blockIdx.x * EPB, i1 = min(i0 + EPB, E);
    for (int i = i0 + t; i < i1; i += 256)
        atomicAdd(&h[(dst[i] >> shift) & 255], 1);
    __syncthreads();
    if (h[t] > 0) atomicAdd(&bhist[t], h[t]);
}

__global__ __launch_bounds__(256) void scan256(const int* __restrict__ h,
                                               int* __restrict__ base, int* __restrict__ cur)
{
    __shared__ int p[256];
    int t = threadIdx.x;
    int v = h[t];
    p[t] = v;
    __syncthreads();
    for (int off = 1; off < 256; off <<= 1) {
        int u = (t >= off) ? p[t - off] : 0;
        __syncthreads();
        p[t] += u;
        __syncthreads();
    }
    base[t] = p[t] - v;
    cur[t]  = p[t] - v;
    if (t == 255) base[256] = p[255];
}

template<bool PAIR>
__global__ __launch_bounds__(256) void partition_edges(
    const int* __restrict__ src, const int* __restrict__ dst, int E, int shift,
    int* __restrict__ cur, int2* __restrict__ tmp_pair, int* __restrict__ out_src)
{
    __shared__ int cnt[256], base[256], cnt2[256];
    int t = threadIdx.x;
    cnt[t] = 0; cnt2[t] = 0;
    __syncthreads();
    int i0 = blockIdx.x * EPB, i1 = min(i0 + EPB, E);
    for (int i = i0 + t; i < i1; i += 256)
        atomicAdd(&cnt[(dst[i] >> shift) & 255], 1);
    __syncthreads();
    if (cnt[t] > 0) base[t] = atomicAdd(&cur[t], cnt[t]);
    __syncthreads();
    for (int i = i0 + t; i < i1; i += 256) {
        int d = dst[i];
        int dig = (d >> shift) & 255;
        int r = atomicAdd(&cnt2[dig], 1);
        int pos = base[dig] + r;
        if constexpr (PAIR) tmp_pair[pos] = make_int2(src[i], d);
        else                out_src[pos] = src[i];
    }
}

__global__ __launch_bounds__(256) void bucket_finalize(
    const int2* __restrict__ tmp, const int* __restrict__ bbase, int n, int NE,
    int* __restrict__ rs, int* __restrict__ csr)
{
    __shared__ int cnt[256], pre[256], cnt2[256];
    int b = blockIdx.x, t = threadIdx.x;
    int s0 = bbase[b], s1 = bbase[b + 1];
    cnt[t] = 0; cnt2[t] = 0;
    __syncthreads();
    for (int i = s0 + t; i < s1; i += 256)
        atomicAdd(&cnt[tmp[i].y & 255], 1);
    __syncthreads();
    int v = cnt[t];
    pre[t] = v;
    __syncthreads();
    for (int off = 1; off < 256; off <<= 1) {
        int u = (t >= off) ? pre[t - off] : 0;
        __syncthreads();
        pre[t] += u;
        __syncthreads();
    }
    pre[t] -= v;   // exclusive
    __syncthreads();
    int dstid = b * 256 + t;
    if (dstid < n) rs[dstid] = s0 + pre[t];
    if (b == 0 && t == 0) rs[n] = NE;
    for (int i = s0 + t; i < s1; i += 256) {
        int2 e = tmp[i];
        int low = e.y & 255;
        int r = atomicAdd(&cnt2[low], 1);
        csr[s0 + pre[low] + r] = e.x;
    }
}

// ---------------- fused q~/k/v GEMM: A[M,128] x 3 weights -> out[M,384] --------
// As row-major [64][128+4]: float4 staging (no transpose, no conflicts);
// compute tile 4 rows x 8 cols per thread, float4 LDS fragment loads.
__global__ __launch_bounds__(256) void gemm_qkv(
    const float* __restrict__ A, int lda, int M,
    const float* __restrict__ W0, const float* __restrict__ W1, const float* __restrict__ W2,
    const float* __restrict__ b0, const float* __restrict__ b1, const float* __restrict__ b2,
    float* __restrict__ out)
{
    __shared__ float As[64][132];   // 33 KB
    __shared__ float Bs[32][128];   // 16 KB
    int tid = threadIdx.x;
    int row0 = blockIdx.x * 64;
    int tx = tid & 15;   // col group -> cols tx*8..+7
    int ty = tid >> 4;   // row group -> rows ty*4..+3
    #pragma unroll
    for (int i = 0; i < 8; i++) {
        int slot = tid + i * 256;            // [0,2048) float4 slots
        int r = slot >> 5, kq = slot & 31;
        int rr = row0 + r;
        float4 v = make_float4(0.f, 0.f, 0.f, 0.f);
        if (rr < M) v = *(const float4*)(A + (size_t)rr * lda + kq * 4);
        *(float4*)&As[r][kq * 4] = v;
    }
    const float* Ws[3] = {W0, W1, W2};
    const float* bs[3] = {b0, b1, b2};
    for (int jw = 0; jw < 3; jw++) {
        float acc[4][8] = {};
        for (int k0 = 0; k0 < 128; k0 += 32) {
            __syncthreads();
            #pragma unroll
            for (int i = 0; i < 4; i++) {
                int slot = tid + i * 256;    // [0,1024)
                int kr = slot >> 5, cq = slot & 31;
                *(float4*)&Bs[kr][cq * 4] = *(const float4*)(Ws[jw] + (size_t)(k0 + kr) * 128 + cq * 4);
            }
            __syncthreads();
            #pragma unroll
            for (int k4 = 0; k4 < 32; k4 += 4) {
                float4 av[4];
                #pragma unroll
                for (int i = 0; i < 4; i++)
                    av[i] = *(const float4*)&As[ty * 4 + i][k0 + k4];
                #pragma unroll
                for (int kk = 0; kk < 4; kk++) {
                    float4 bl = *(const float4*)&Bs[k4 + kk][tx * 8];
                    float4 bh = *(const float4*)&Bs[k4 + kk][tx * 8 + 4];
                    float bb[8] = {bl.x, bl.y, bl.z, bl.w, bh.x, bh.y, bh.z, bh.w};
                    #pragma unroll
                    for (int i = 0; i < 4; i++) {
                        float a = ((const float*)&av[i])[kk];
                        #pragma unroll
                        for (int j = 0; j < 8; j++)
                            acc[i][j] = fmaf(a, bb[j], acc[i][j]);
                    }
                }
            }
        }
        #pragma unroll
        for (int i = 0; i < 4; i++) {
            int r = row0 + ty * 4 + i;
            if (r >= M) continue;
            float4 o0 = make_float4(acc[i][0] + bs[jw][tx * 8 + 0],
                                    acc[i][1] + bs[jw][tx * 8 + 1],
                                    acc[i][2] + bs[jw][tx * 8 + 2],
                                    acc[i][3] + bs[jw][tx * 8 + 3]);
            float4 o1 = make_float4(acc[i][4] + bs[jw][tx * 8 + 4],
                                    acc[i][5] + bs[jw][tx * 8 + 5],
                                    acc[i][6] + bs[jw][tx * 8 + 6],
                                    acc[i][7] + bs[jw][tx * 8 + 7]);
            float* op = out + (size_t)r * 384 + jw * 128 + tx * 8;
            *(float4*)op = o0;
            *(float4*)(op + 4) = o1;
        }
    }
}

// ---------------- fp32 GEMM: out[M,128] = A[M,lda,128] @ W + bias --------------
// optional skip epilogue (gate/xold); optional fused out-conv k/v projections.
__global__ __launch_bounds__(256) void gemm128(
    const float* __restrict__ A, int lda, const float* __restrict__ W,
    const float* __restrict__ bias, float* out, int M,
    const float* __restrict__ gate, const float* __restrict__ xold,
    const float* __restrict__ wk_o, const float* __restrict__ bk_o, float* __restrict__ ko,
    const float* __restrict__ wv_o, const float* __restrict__ bv_o, float* __restrict__ vo)
{
    __shared__ float As[64][36];    // 9 KB (32-wide k-tile, +4 pad)
    __shared__ float Bs[32][128];   // 16 KB
    int tid = threadIdx.x;
    int row0 = blockIdx.x * 64;
    int tx = tid & 15;
    int ty = tid >> 4;
    float acc[4][8] = {};
    for (int k0 = 0; k0 < 128; k0 += 32) {
        __syncthreads();
        #pragma unroll
        for (int i = 0; i < 2; i++) {
            int slot = tid + i * 256;            // [0,512) float4 slots
            int r = slot >> 3, kq = slot & 7;
            int rr = row0 + r;
            float4 v = make_float4(0.f, 0.f, 0.f, 0.f);
            if (rr < M) v = *(const float4*)(A + (size_t)rr * lda + k0 + kq * 4);
            *(float4*)&As[r][kq * 4] = v;
        }
        #pragma unroll
        for (int i = 0; i < 4; i++) {
            int slot = tid + i * 256;            // [0,1024)
            int kr = slot >> 5, cq = slot & 31;
            *(float4*)&Bs[kr][cq * 4] = *(const float4*)(W + (size_t)(k0 + kr) * 128 + cq * 4);
        }
        __syncthreads();
        #pragma unroll
        for (int k4 = 0; k4 < 32; k4 += 4) {
            float4 av[4];
            #pragma unroll
            for (int i = 0; i < 4; i++)
                av[i] = *(const float4*)&As[ty * 4 + i][k4];
            #pragma unroll
            for (int kk = 0; kk < 4; kk++) {
                float4 bl = *(const float4*)&Bs[k4 + kk][tx * 8];
                float4 bh = *(const float4*)&Bs[k4 + kk][tx * 8 + 4];
                float bb[8] = {bl.x, bl.y, bl.z, bl.w, bh.x, bh.y, bh.z, bh.w};
                #pragma unroll
                for (int i = 0; i < 4; i++) {
                    float a = ((const float*)&av[i])[kk];
                    #pragma unroll
                    for (int j = 0; j < 8; j++)
                        acc[i][j] = fmaf(a, bb[j], acc[i][j]);
                }
            }
        }
    }
    float g = 1.f, og = 0.f;
    if (gate != nullptr) { g = 1.f / (1.f + expf(-gate[0])); og = 1.f - g; }
    float wkr[8], wvr[8];
    if (wk_o != nullptr) {
        #pragma unroll
        for (int j = 0; j < 8; j++) {
            wkr[j] = wk_o[tx * 8 + j];
            wvr[j] = wv_o[tx * 8 + j];
        }
    }
    #pragma unroll
    for (int i = 0; i < 4; i++) {
        int r = row0 + ty * 4 + i;
        if (r >= M) continue;   // uniform across each 16-lane group (r depends on ty only)
        float vals[8];
        #pragma unroll
        for (int j = 0; j < 8; j++) {
            float v = acc[i][j] + bias[tx * 8 + j];
            if (gate != nullptr) v = g * v + og * xold[(size_t)r * 128 + tx * 8 + j];
            vals[j] = v;
        }
        float* op = out + (size_t)r * 128 + tx * 8;
        *(float4*)op = make_float4(vals[0], vals[1], vals[2], vals[3]);
        *(float4*)(op + 4) = make_float4(vals[4], vals[5], vals[6], vals[7]);
        if (wk_o != nullptr) {
            float pk = 0.f, pv = 0.f;
            #pragma unroll
            for (int j = 0; j < 8; j++) {
                pk = fmaf(vals[j], wkr[j], pk);
                pv = fmaf(vals[j], wvr[j], pv);
            }
            #pragma unroll
            for (int off = 1; off < 16; off <<= 1) {
                pk += __shfl_xor(pk, off, 64);
                pv += __shfl_xor(pv, off, 64);
            }
            if (tx == 0) {
                ko[r] = pk + bk_o[0];
                vo[r] = pv + bv_o[0];
            }
        }
    }
}

// ---------------- group-of-16 edge accumulation (4 edges in flight + 2x unroll)
__device__ __forceinline__ void accum_g16(
    const float* __restrict__ xqkv, const int* __restrict__ csr,
    int e0, int e1, int g, float4 qa, float4 qb, float& s_io, float acc[8])
{
    float s = 0.f;
    int e = e0 + g;
    for (; e + 4 < e1; e += 8) {
        int i0 = csr[e], i1 = csr[e + 4];
        const float* p0 = xqkv + (size_t)i0 * 384 + 128 + ((threadIdx.x & 15) * 8);
        const float* p1 = xqkv + (size_t)i1 * 384 + 128 + ((threadIdx.x & 15) * 8);
        float4 k0a = *(const float4*)p0,         k0b = *(const float4*)(p0 + 4);
        float4 v0a = *(const float4*)(p0 + 128), v0b = *(const float4*)(p0 + 132);
        float4 k1a = *(const float4*)p1,         k1b = *(const float4*)(p1 + 4);
        float4 v1a = *(const float4*)(p1 + 128), v1b = *(const float4*)(p1 + 132);
        float d0 = dot8(qa, qb, k0a, k0b);
        float d1 = dot8(qa, qb, k1a, k1b);
        d0 += __shfl_xor(d0, 1, 64); d1 += __shfl_xor(d1, 1, 64);
        d0 += __shfl_xor(d0, 2, 64); d1 += __shfl_xor(d1, 2, 64);
        float w0 = __expf(d0), w1 = __expf(d1);
        s += w0 + w1;
        acc[0] = fmaf(w0, v0a.x, acc[0]); acc[0] = fmaf(w1, v1a.x, acc[0]);
        acc[1] = fmaf(w0, v0a.y, acc[1]); acc[1] = fmaf(w1, v1a.y, acc[1]);
        acc[2] = fmaf(w0, v0a.z, acc[2]); acc[2] = fmaf(w1, v1a.z, acc[2]);
        acc[3] = fmaf(w0, v0a.w, acc[3]); acc[3] = fmaf(w1, v1a.w, acc[3]);
        acc[4] = fmaf(w0, v0b.x, acc[4]); acc[4] = fmaf(w1, v1b.x, acc[4]);
        acc[5] = fmaf(w0, v0b.y, acc[5]); acc[5] = fmaf(w1, v1b.y, acc[5]);
        acc[6] = fmaf(w0, v0b.z, acc[6]); acc[6] = fmaf(w1, v1b.z, acc[6]);
        acc[7] = fmaf(w0, v0b.w, acc[7]); acc[7] = fmaf(w1, v1b.w, acc[7]);
    }
    if (e < e1) {
        int i0 = csr[e];
        const float* p0 = xqkv + (size_t)i0 * 384 + 128 + ((threadIdx.x & 15) * 8);
        float4 k0a = *(const float4*)p0,         k0b = *(const float4*)(p0 + 4);
        float4 v0a = *(const float4*)(p0 + 128), v0b = *(const float4*)(p0 + 132);
        float d0 = dot8(qa, qb, k0a, k0b);
        d0 += __shfl_xor(d0, 1, 64);
        d0 += __shfl_xor(d0, 2, 64);
        float w0 = __expf(d0);
        s += w0;
        acc[0] = fmaf(w0, v0a.x, acc[0]);
        acc[1] = fmaf(w0, v0a.y, acc[1]);
        acc[2] = fmaf(w0, v0a.z, acc[2]);
        acc[3] = fmaf(w0, v0a.w, acc[3]);
        acc[4] = fmaf(w0, v0b.x, acc[4]);
        acc[5] = fmaf(w0, v0b.y, acc[5]);
        acc[6] = fmaf(w0, v0b.z, acc[6]);
        acc[7] = fmaf(w0, v0b.w, acc[7]);
    }
    s_io = s;
}

// ---------------- cc attention: wave/node, NO block barrier, fused mrel+gelu ---
__global__ __launch_bounds__(256) void attn_cc(
    float* xqkv, const int* __restrict__ rowstart, const int* __restrict__ csr,
    const float* __restrict__ mrel, int n)
{
    __shared__ float rowbuf[4][144];
    int lane = threadIdx.x & 63, wid = threadIdx.x >> 6;
    int node = blockIdx.x * 4 + wid;
    if (node >= n) return;
    int g = lane >> 4, j = lane & 15;
    const float* qp = xqkv + (size_t)node * 384 + 8 * j;
    float4 qa = *(const float4*)qp, qb = *(const float4*)(qp + 4);
    int rs = rowstart[node], re = rowstart[node + 1];
    float s = 0.f;
    float acc[8] = {};
    accum_g16(xqkv, csr, rs, re, g, qa, qb, s, acc);
    #pragma unroll
    for (int i = 0; i < 8; i++) {
        acc[i] += __shfl_xor(acc[i], 16, 64);
        acc[i] += __shfl_xor(acc[i], 32, 64);
    }
    s += __shfl_xor(s, 16, 64);
    s += __shfl_xor(s, 32, 64);
    float inv = (s > 0.f) ? 1.f / s : 0.f;
    if (g == 0) {
        int off = 8 * j + 4 * (j >> 2);   // +4 pad per head
        float4 o0 = make_float4(acc[0] * inv, acc[1] * inv, acc[2] * inv, acc[3] * inv);
        float4 o1 = make_float4(acc[4] * inv, acc[5] * inv, acc[6] * inv, acc[7] * inv);
        *(float4*)&rowbuf[wid][off]     = o0;
        *(float4*)&rowbuf[wid][off + 4] = o1;
    }
    int lp = 2 * lane;
    int h = lp >> 5, eo = lp & 31;
    const float* mr = mrel + h * 1024 + eo;
    const float* rb = rowbuf[wid] + 36 * h;
    float t0 = 0.f, t1 = 0.f;
    #pragma unroll
    for (int d = 0; d < 32; d++) {
        float a = rb[d];
        t0 = fmaf(a, mr[d * 32], t0);
        t1 = fmaf(a, mr[d * 32 + 1], t1);
    }
    float2 o = make_float2(gelu_tanh(t0), gelu_tanh(t1));
    *(float2*)(xqkv + (size_t)node * 384 + lp) = o;
}

// ---------------- cv attention: block/node (16 waves x 4 groups), fused --------
__global__ __launch_bounds__(1024) void attn_cv(
    const float* __restrict__ qtv, const float* __restrict__ xqkv,
    const int* __restrict__ rowstart, const int* __restrict__ csr,
    const float* __restrict__ mrel, float* __restrict__ aggv)
{
    __shared__ float sm_s[16][4];
    __shared__ float sm_a[16][128];
    __shared__ float orow[144];
    int lane = threadIdx.x & 63, w = threadIdx.x >> 6;
    int node = blockIdx.x;
    int g = lane >> 4, j = lane & 15;
    const float* qp = qtv + (size_t)node * 128 + 8 * j;
    float4 qa = *(const float4*)qp, qb = *(const float4*)(qp + 4);
    int rs = rowstart[node], re = rowstart[node + 1];
    int cnt = re - rs;
    int per = (cnt + 15) >> 4;
    int e0 = rs + w * per, e1 = min(e0 + per, re);
    float s = 0.f;
    float acc[8] = {};
    accum_g16(xqkv, csr, e0, e1, g, qa, qb, s, acc);
    #pragma unroll
    for (int i = 0; i < 8; i++) {
        acc[i] += __shfl_xor(acc[i], 16, 64);
        acc[i] += __shfl_xor(acc[i], 32, 64);
    }
    s += __shfl_xor(s, 16, 64);
    s += __shfl_xor(s, 32, 64);
    if (g == 0) {
        *(float4*)&sm_a[w][8 * j]     = make_float4(acc[0], acc[1], acc[2], acc[3]);
        *(float4*)&sm_a[w][8 * j + 4] = make_float4(acc[4], acc[5], acc[6], acc[7]);
        if ((j & 3) == 0) sm_s[w][j >> 2] = s;
    }
    __syncthreads();
    if (threadIdx.x < 64) {
        int lp = 2 * lane;
        int h = lp >> 5;
        float S = 0.f, AX = 0.f, AY = 0.f;
        #pragma unroll
        for (int i = 0; i < 16; i++) {
            S  += sm_s[i][h];
            float2 a2 = *(const float2*)&sm_a[i][lp];
            AX += a2.x;
            AY += a2.y;
        }
        float inv = (S > 0.f) ? 1.f / S : 0.f;
        int off = lp + 4 * h;   // padded
        orow[off]     = AX * inv;
        orow[off + 1] = AY * inv;
        int eo = lp & 31;
        const float* mr = mrel + h * 1024 + eo;
        const float* rb = orow + 36 * h;
        float t0 = 0.f, t1 = 0.f;
        #pragma unroll
        for (int d = 0; d < 32; d++) {
            float a = rb[d];
            t0 = fmaf(a, mr[d * 32], t0);
            t1 = fmaf(a, mr[d * 32 + 1], t1);
        }
        aggv[(size_t)node * 128 + lp]     = gelu_tanh(t0);
        aggv[(size_t)node * 128 + lp + 1] = gelu_tanh(t1);
    }
}

// ---------------- out-conv projections (C -> 1), wave per row -----------------
__global__ __launch_bounds__(256) void proj2(const float* __restrict__ x, int n,
    const float* __restrict__ w1, const float* __restrict__ b1, float* __restrict__ o1,
    const float* __restrict__ w2, const float* __restrict__ b2, float* __restrict__ o2)
{
    int lane = threadIdx.x & 63;
    int wid = threadIdx.x >> 6;
    int r = blockIdx.x * 4 + wid;
    if (r >= n) return;
    float x0 = x[(size_t)r * 128 + lane], x1 = x[(size_t)r * 128 + 64 + lane];
    float p = fmaf(x0, w1[lane], x1 * w1[64 + lane]);
    #pragma unroll
    for (int off = 32; off >= 1; off >>= 1) p += __shfl_xor(p, off, 64);
    if (lane == 0) o1[r] = p + b1[0];
    if (o2 != nullptr) {
        float q = fmaf(x0, w2[lane], x1 * w2[64 + lane]);
        #pragma unroll
        for (int off = 32; off >= 1; off >>= 1) q += __shfl_xor(q, off, 64);
        if (lane == 0) o2[r] = q + b2[0];
    }
}

// ---------------- out-conv scalar attention (block per vnode, max-free) --------
__global__ __launch_bounds__(256) void attn_out(
    const float* __restrict__ qo, const float* __restrict__ ko, const float* __restrict__ vo,
    const int* __restrict__ rowstart, const int* __restrict__ csr,
    const float* __restrict__ arel_o, const float* __restrict__ prel_o,
    const float* __restrict__ mrel_o, const float* __restrict__ Wa_o,
    const float* __restrict__ ba_o, float* __restrict__ outl)
{
    int node = blockIdx.x;
    float qs = qo[node] * arel_o[0] * prel_o[0];
    int rs = rowstart[node], re = rowstart[node + 1];
    float s = 0.f, a = 0.f;
    for (int e = rs + (int)threadIdx.x; e < re; e += 256) {
        int si = csr[e];
        float w = __expf(qs * ko[si]);
        s += w;
        a = fmaf(w, vo[si], a);
    }
    #pragma unroll
    for (int off = 32; off >= 1; off >>= 1) {
        s += __shfl_xor(s, off, 64);
        a += __shfl_xor(a, off, 64);
    }
    __shared__ float sms[4], sma[4];
    int lane = threadIdx.x & 63, wid = threadIdx.x >> 6;
    if (lane == 0) { sms[wid] = s; sma[wid] = a; }
    __syncthreads();
    if (threadIdx.x == 0) {
        float S = sms[0] + sms[1] + sms[2] + sms[3];
        float A = sma[0] + sma[1] + sma[2] + sma[3];
        float agg = (S > 0.f) ? A / S : 0.f;
        agg *= mrel_o[0];
        outl[node] = gelu_tanh(agg) * Wa_o[0] + ba_o[0];
    }
}

// ---------------- final head: JK-max -> node_fc -> MLP ------------------------
__global__ void final_head(const float* __restrict__ outs,
    const float* __restrict__ fc_W, const float* __restrict__ fc_b,
    const float* __restrict__ W1, const float* __restrict__ b1,
    const float* __restrict__ W2, const float* __restrict__ b2,
    float* __restrict__ out)
{
    int b = threadIdx.x;
    if (b >= 64) return;
    float h = fc_b[0];
    #pragma unroll
    for (int v = 0; v < 4; v++) {
        int n = b * 4 + v;
        float jk = fmaxf(fmaxf(outs[0 * N_V + n], outs[1 * N_V + n]), outs[2 * N_V + n]);
        h = fmaf(jk, fc_W[v], h);
    }
    h = gelu_tanh(h);
    float h0 = gelu_tanh(h * W1[0] + b1[0]);
    float h1 = gelu_tanh(h * W1[1] + b1[1]);
    out[b] = h0 * W2[0] + h1 * W2[1] + b2[0];
}

// ---------------- orchestration ----------------------------------------------
extern "C" void kernel_launch(void* const* d_in, const int* in_sizes, int n_in,
                              void* d_out, int out_size, void* d_ws, size_t ws_size,
                              hipStream_t stream) {
    (void)in_sizes; (void)n_in; (void)out_size; (void)ws_size;
    const float* x_cell  = (const float*)d_in[0];
    const float* x_vcell = (const float*)d_in[1];
    const float* Wk   = (const float*)d_in[2];
    const float* bk   = (const float*)d_in[3];
    const float* Wq   = (const float*)d_in[4];
    const float* bq   = (const float*)d_in[5];
    const float* Wv   = (const float*)d_in[6];
    const float* bv   = (const float*)d_in[7];
    const float* Wa   = (const float*)d_in[8];
    const float* ba   = (const float*)d_in[9];
    const float* skip = (const float*)d_in[10];
    const float* arel = (const float*)d_in[11];
    const float* mrel = (const float*)d_in[12];
    const float* prel = (const float*)d_in[13];
    const float* Wk_o = (const float*)d_in[14];
    const float* bk_o = (const float*)d_in[15];
    const float* Wq_o = (const float*)d_in[16];
    const float* bq_o = (const float*)d_in[17];
    const float* Wv_o = (const float*)d_in[18];
    const float* bv_o = (const float*)d_in[19];
    const float* Wa_o = (const float*)d_in[20];
    const float* ba_o = (const float*)d_in[21];
    const float* arel_o = (const float*)d_in[22];
    const float* mrel_o = (const float*)d_in[23];
    const float* prel_o = (const float*)d_in[24];
    const float* fc_W  = (const float*)d_in[25];
    const float* fc_b  = (const float*)d_in[26];
    const float* mlp_W1 = (const float*)d_in[27];
    const float* mlp_b1 = (const float*)d_in[28];
    const float* mlp_W2 = (const float*)d_in[29];
    const float* mlp_b2 = (const float*)d_in[30];
    const int* src_cc = (const int*)d_in[31];
    const int* dst_cc = (const int*)d_in[32];
    const int* src_cv = (const int*)d_in[33];
    const int* dst_cv = (const int*)d_in[34];

    // workspace carve-up (256B aligned)
    char* p = (char*)d_ws;
    auto alloc = [&](size_t bytes) -> char* {
        uintptr_t q = ((uintptr_t)p + 255) & ~(uintptr_t)255;
        p = (char*)(q + bytes);
        return (char*)q;
    };
    float* WQT  = (float*)alloc(sizeof(float) * NL * 2 * CH * CH);
    float* BQT  = (float*)alloc(sizeof(float) * NL * 2 * CH);
    float* XC   = (float*)alloc(sizeof(float) * (size_t)N_C * CH);
    float* XV   = (float*)alloc(sizeof(float) * (size_t)N_V * CH);
    float* XQKV = (float*)alloc(sizeof(float) * (size_t)N_C * 384);  // [q~|k|v] per node
    float* QTV  = (float*)alloc(sizeof(float) * (size_t)N_V * CH);
    float* AGGV = (float*)alloc(sizeof(float) * (size_t)N_V * CH);
    float* KO   = (float*)alloc(sizeof(float) * N_C);
    float* VO   = (float*)alloc(sizeof(float) * N_C);
    float* QO   = (float*)alloc(sizeof(float) * N_V);
    float* OUTS = (float*)alloc(sizeof(float) * NL * N_V);
    // CSR-build scratch
    int* bhist    = (int*)alloc(sizeof(int) * 512);
    int* bhist_cc = bhist;
    int* bhist_cv = bhist + 256;
    int* bbase_cc = (int*)alloc(sizeof(int) * 257);
    int* cur_cc   = (int*)alloc(sizeof(int) * 256);
    int* cur_cv   = (int*)alloc(sizeof(int) * 256);
    int* rs_cc    = (int*)alloc(sizeof(int) * (N_C + 1));
    int* rs_cv    = (int*)alloc(sizeof(int) * (N_V + 1));
    int* csr_cc   = (int*)alloc(sizeof(int) * NE1);
    int* csr_cv   = (int*)alloc(sizeof(int) * NE2);
    int2* tmp_cc  = (int2*)alloc(sizeof(int2) * NE1);

    // ---- setup: composed weights + CSR (two-level counting sort) ----
    compose_wq<<<CDIV(NL * 2 * (CH + 1) * CH, 256), 256, 0, stream>>>(
        Wq, bq, arel, prel, WQT, BQT);
    hipMemsetAsync(bhist, 0, sizeof(int) * 512, stream);
    bucket_hist<<<CDIV(NE1, EPB), 256, 0, stream>>>(dst_cc, NE1, 8, bhist_cc);
    bucket_hist<<<CDIV(NE2, EPB), 256, 0, stream>>>(dst_cv, NE2, 0, bhist_cv);
    scan256<<<1, 256, 0, stream>>>(bhist_cc, bbase_cc, cur_cc);
    scan256<<<1, 256, 0, stream>>>(bhist_cv, rs_cv, cur_cv);   // rs_cv IS the cv row starts
    partition_edges<true ><<<CDIV(NE1, EPB), 256, 0, stream>>>(src_cc, dst_cc, NE1, 8,
                                                               cur_cc, tmp_cc, nullptr);
    partition_edges<false><<<CDIV(NE2, EPB), 256, 0, stream>>>(src_cv, dst_cv, NE2, 0,
                                                               cur_cv, nullptr, csr_cv);
    bucket_finalize<<<CDIV(N_C, 256), 256, 0, stream>>>(tmp_cc, bbase_cc, N_C, NE1,
                                                        rs_cc, csr_cc);

    const int gb_c = CDIV(N_C, 64);
    const int gb_v = CDIV(N_V, 64);

    for (int li = 0; li < NL; li++) {
        const float* xc_src = (li == 0) ? x_cell : XC;
        const float* xv_src = (li == 0) ? x_vcell : XV;
        size_t w0 = (size_t)(li * 2) * CH * CH;
        size_t w1 = (size_t)(li * 2 + 1) * CH * CH;
        int b0 = (li * 2) * CH, b1 = (li * 2 + 1) * CH;

        // fused q~/k/v GEMM -> XQKV[n] = [q~|k|v]; q~v (NV x 128)
        gemm_qkv<<<gb_c, 256, 0, stream>>>(xc_src, 128, N_C,
                                           WQT + w0, Wk + w0, Wv + w0,
                                           BQT + b0, bk + b0, bv + b0, XQKV);
        gemm128<<<gb_v, 256, 0, stream>>>(xv_src, 128, WQT + w1, BQT + b1, QTV, N_V,
                                          nullptr, nullptr,
                                          nullptr, nullptr, nullptr, nullptr, nullptr, nullptr);

        // cc attention (max-free, group-of-16, fused mrel+gelu, in-place q~ slot)
        attn_cc<<<CDIV(N_C, 4), 256, 0, stream>>>(XQKV, rs_cc, csr_cc,
                                                  mrel + (size_t)(li * 2) * NH * HD * HD, N_C);
        // cv attention
        attn_cv<<<N_V, 1024, 0, stream>>>(QTV, XQKV, rs_cv, csr_cv,
                                          mrel + (size_t)(li * 2 + 1) * NH * HD * HD, AGGV);

        // Wa GEMMs with skip epilogue; c-side fuses out-conv k/v projections
        gemm128<<<gb_c, 256, 0, stream>>>(XQKV, 384, Wa + w0, ba + b0, XC, N_C,
                                          skip + li * 2, xc_src,
                                          Wk_o + li * CH, bk_o + li, KO,
                                          Wv_o + li * CH, bv_o + li, VO);
        gemm128<<<gb_v, 256, 0, stream>>>(AGGV, 128, Wa + w1, ba + b1, XV, N_V,
                                          skip + li * 2 + 1, xv_src,
                                          nullptr, nullptr, nullptr, nullptr, nullptr, nullptr);

        // out-conv: q projection on vnodes + scalar attention on cv edges
        proj2<<<CDIV(N_V, 4), 256, 0, stream>>>(XV, N_V, Wq_o + li * CH, bq_o + li, QO,
                                                nullptr, nullptr, nullptr);
        attn_out<<<N_V, 256, 0, stream>>>(QO, KO, VO, rs_cv, csr_cv,
                                          arel_o + li, prel_o + li, mrel_o + li,
                                          Wa_o + li, ba_o + li, OUTS + li * N_V);
    }

    final_head<<<1, 64, 0, stream>>>(OUTS, fc_W, fc_b, mlp_W1, mlp_b1, mlp_W2, mlp_b2,
                                     (float*)d_out);
}